// Round 1
// baseline (3102.794 us; speedup 1.0000x reference)
//
#include <hip/hip_runtime.h>
#include <math.h>

#define AT 1024
#define NBR 32
#define FN 128
#define FE 128
#define ZIN 384
#define NA 4096              // B*At
#define NEDGE (NA * NBR)     // 131072
#define WSTRIDE (ZIN * FN)   // 49152 floats per layer
#define EOFF (2 * FN * FN)   // 32768: offset of the e-part rows in W
#define G_ENDF 5.5f

__device__ __forceinline__ float sigmoid_f(float x) {
    return 1.0f / (1.0f + expf(-x));
}
__device__ __forceinline__ float softplus_f(float x) {
    // stable: max(x,0) + log1p(exp(-|x|))
    return fmaxf(x, 0.0f) + log1pf(expf(-fabsf(x)));
}

// -------- h0[atom][f] = emb[Z[atom]][f] --------
__global__ __launch_bounds__(256) void k_init_h(const int* __restrict__ Z,
                                                const float* __restrict__ emb,
                                                float* __restrict__ h) {
    int idx = blockIdx.x * 256 + threadIdx.x;  // over NA*FN
    int atom = idx >> 7, f = idx & 127;
    h[idx] = emb[Z[atom] * FN + f];
}

// -------- e[edge][f] = exp(coeff*(d - f*delta)^2) --------
__global__ __launch_bounds__(256) void k_init_e(const float* __restrict__ dist,
                                                float* __restrict__ e) {
    int idx = blockIdx.x * 256 + threadIdx.x;  // over NEDGE*FE
    int edge = idx >> 7, f = idx & 127;
    const float delta = G_ENDF / 127.0f;
    const float coeff = -0.5f / (delta * delta);
    float d = dist[edge] - (float)f * delta;
    e[idx] = expf(coeff * d * d);
}

// -------- per-node projections: Pi = h@W[0:128] + bias, Pj = h@W[128:256] --------
__global__ __launch_bounds__(128) void k_node_proj(const float* __restrict__ h,
                                                   const float* __restrict__ W,
                                                   const float* __restrict__ bias,
                                                   float* __restrict__ Pi,
                                                   float* __restrict__ Pj) {
    const int f = threadIdx.x;          // 0..127
    const int a0 = blockIdx.x * 16;     // 16 atoms per block
    __shared__ __align__(16) float sh[16 * 128];

    const float4* h4 = (const float4*)(h + (size_t)a0 * 128);
    float4* sh4 = (float4*)sh;
#pragma unroll
    for (int i = 0; i < 4; ++i) sh4[i * 128 + f] = h4[i * 128 + f];
    __syncthreads();

    float acc_i[16], acc_j[16];
    float b = bias[f];
#pragma unroll
    for (int a = 0; a < 16; ++a) { acc_i[a] = b; acc_j[a] = 0.0f; }

    for (int k = 0; k < 128; ++k) {
        float wa = W[k * 128 + f];
        float wb = W[(128 + k) * 128 + f];
#pragma unroll
        for (int a = 0; a < 16; ++a) {
            float hk = sh[a * 128 + k];
            acc_i[a] = fmaf(hk, wa, acc_i[a]);
            acc_j[a] = fmaf(hk, wb, acc_j[a]);
        }
    }
#pragma unroll
    for (int a = 0; a < 16; ++a) {
        Pi[(size_t)(a0 + a) * 128 + f] = acc_i[a];
        Pj[(size_t)(a0 + a) * 128 + f] = acc_j[a];
    }
}

// -------- node update: h_new[a] = h_old[a] + sum_n sigmoid(zf)*softplus(zc) --------
// block = 1 atom, 512 threads = 4 edge-slots x 128 features
__global__ __launch_bounds__(512) void k_node_update(
    const float* __restrict__ e, const int* __restrict__ nbr,
    const float* __restrict__ Pfi, const float* __restrict__ Pfj,
    const float* __restrict__ Pci, const float* __restrict__ Pcj,
    const float* __restrict__ WfE, const float* __restrict__ WcE,
    const float* __restrict__ h_old, float* __restrict__ h_new) {
    const int tid = threadIdx.x;
    const int f = tid & 127;
    const int ns = tid >> 7;  // 0..3
    const int atom = blockIdx.x;
    const int base = atom & ~(AT - 1);

    __shared__ __align__(16) float sWf[128 * 128];
    __shared__ __align__(16) float sWc[128 * 128];
    __shared__ __align__(16) float se[4][128];
    __shared__ __align__(16) float sred[4][128];
    __shared__ int snbr[32];

    {
        const float4* a4 = (const float4*)WfE;
        const float4* b4 = (const float4*)WcE;
        float4* s4 = (float4*)sWf;
        float4* t4 = (float4*)sWc;
#pragma unroll
        for (int i = 0; i < 8; ++i) {
            s4[i * 512 + tid] = a4[i * 512 + tid];
            t4[i * 512 + tid] = b4[i * 512 + tid];
        }
    }
    if (tid < 32) snbr[tid] = nbr[atom * 32 + tid];
    __syncthreads();

    const float pfi = Pfi[(size_t)atom * 128 + f];
    const float pci = Pci[(size_t)atom * 128 + f];
    float hacc = 0.0f;

    for (int n0 = 0; n0 < 32; n0 += 4) {
        const int n = n0 + ns;
        se[ns][f] = e[((size_t)atom * 32 + n) * 128 + f];
        __syncthreads();

        const int j = base + snbr[n];
        float af = pfi + Pfj[(size_t)j * 128 + f];
        float ac = pci + Pcj[(size_t)j * 128 + f];

        const float4* se4 = (const float4*)&se[ns][0];
#pragma unroll
        for (int kq = 0; kq < 32; ++kq) {
            float4 ev = se4[kq];
            int kb = kq * 4;
            af = fmaf(ev.x, sWf[(kb + 0) * 128 + f], af);
            ac = fmaf(ev.x, sWc[(kb + 0) * 128 + f], ac);
            af = fmaf(ev.y, sWf[(kb + 1) * 128 + f], af);
            ac = fmaf(ev.y, sWc[(kb + 1) * 128 + f], ac);
            af = fmaf(ev.z, sWf[(kb + 2) * 128 + f], af);
            ac = fmaf(ev.z, sWc[(kb + 2) * 128 + f], ac);
            af = fmaf(ev.w, sWf[(kb + 3) * 128 + f], af);
            ac = fmaf(ev.w, sWc[(kb + 3) * 128 + f], ac);
        }
        hacc += sigmoid_f(af) * softplus_f(ac);
        __syncthreads();
    }

    sred[ns][f] = hacc;
    __syncthreads();
    if (ns == 0) {
        h_new[(size_t)atom * 128 + f] =
            h_old[(size_t)atom * 128 + f] + sred[0][f] + sred[1][f] + sred[2][f] + sred[3][f];
    }
}

// -------- edge update: e[edge] += sigmoid(zf)*softplus(zc)  (in place) --------
__global__ __launch_bounds__(512) void k_edge_update(
    float* __restrict__ e, const int* __restrict__ nbr,
    const float* __restrict__ Pfi, const float* __restrict__ Pfj,
    const float* __restrict__ Pci, const float* __restrict__ Pcj,
    const float* __restrict__ WfE, const float* __restrict__ WcE) {
    const int tid = threadIdx.x;
    const int f = tid & 127;
    const int ns = tid >> 7;
    const int atom = blockIdx.x;
    const int base = atom & ~(AT - 1);

    __shared__ __align__(16) float sWf[128 * 128];
    __shared__ __align__(16) float sWc[128 * 128];
    __shared__ __align__(16) float se[4][128];
    __shared__ int snbr[32];

    {
        const float4* a4 = (const float4*)WfE;
        const float4* b4 = (const float4*)WcE;
        float4* s4 = (float4*)sWf;
        float4* t4 = (float4*)sWc;
#pragma unroll
        for (int i = 0; i < 8; ++i) {
            s4[i * 512 + tid] = a4[i * 512 + tid];
            t4[i * 512 + tid] = b4[i * 512 + tid];
        }
    }
    if (tid < 32) snbr[tid] = nbr[atom * 32 + tid];
    __syncthreads();

    const float pfi = Pfi[(size_t)atom * 128 + f];
    const float pci = Pci[(size_t)atom * 128 + f];

    for (int n0 = 0; n0 < 32; n0 += 4) {
        const int n = n0 + ns;
        const size_t eoff = ((size_t)atom * 32 + n) * 128 + f;
        se[ns][f] = e[eoff];
        __syncthreads();

        const int j = base + snbr[n];
        float af = pfi + Pfj[(size_t)j * 128 + f];
        float ac = pci + Pcj[(size_t)j * 128 + f];

        const float4* se4 = (const float4*)&se[ns][0];
#pragma unroll
        for (int kq = 0; kq < 32; ++kq) {
            float4 ev = se4[kq];
            int kb = kq * 4;
            af = fmaf(ev.x, sWf[(kb + 0) * 128 + f], af);
            ac = fmaf(ev.x, sWc[(kb + 0) * 128 + f], ac);
            af = fmaf(ev.y, sWf[(kb + 1) * 128 + f], af);
            ac = fmaf(ev.y, sWc[(kb + 1) * 128 + f], ac);
            af = fmaf(ev.z, sWf[(kb + 2) * 128 + f], af);
            ac = fmaf(ev.z, sWc[(kb + 2) * 128 + f], ac);
            af = fmaf(ev.w, sWf[(kb + 3) * 128 + f], af);
            ac = fmaf(ev.w, sWc[(kb + 3) * 128 + f], ac);
        }
        e[eoff] = se[ns][f] + sigmoid_f(af) * softplus_f(ac);
        __syncthreads();
    }
}

// -------- output: fm = softplus(e@Wo1+bo1)@Wo2 + bo2 ; forces = sum_n fm*unit --------
// block = 1 atom, 128 threads = 2 waves, each wave does one edge (64 hidden units)
__global__ __launch_bounds__(128) void k_output(
    const float* __restrict__ e, const float* __restrict__ Wo1,
    const float* __restrict__ bo1, const float* __restrict__ Wo2,
    const float* __restrict__ bo2, const float* __restrict__ unit,
    float* __restrict__ out) {
    const int tid = threadIdx.x;
    const int atom = blockIdx.x;
    const int lane = tid & 63;
    const int sub = tid >> 6;  // 0 or 1

    __shared__ __align__(16) float sW[128 * 64];
    __shared__ __align__(16) float se[2][128];
    __shared__ float sfm[32];

    {
        const float4* w4 = (const float4*)Wo1;
        float4* s4 = (float4*)sW;
#pragma unroll
        for (int i = 0; i < 16; ++i) s4[i * 128 + tid] = w4[i * 128 + tid];
    }
    const float b1 = bo1[lane];
    const float w2 = Wo2[lane];
    const float b2 = bo2[0];
    __syncthreads();

    for (int n0 = 0; n0 < 32; n0 += 2) {
        se[0][tid & 127] = e[((size_t)atom * 32 + n0) * 128 + (tid & 127)];
        se[1][tid & 127] = e[((size_t)atom * 32 + n0 + 1) * 128 + (tid & 127)];
        __syncthreads();

        float acc = b1;
        const float4* se4 = (const float4*)&se[sub][0];
#pragma unroll
        for (int kq = 0; kq < 32; ++kq) {
            float4 ev = se4[kq];
            int kb = kq * 4;
            acc = fmaf(ev.x, sW[(kb + 0) * 64 + lane], acc);
            acc = fmaf(ev.y, sW[(kb + 1) * 64 + lane], acc);
            acc = fmaf(ev.z, sW[(kb + 2) * 64 + lane], acc);
            acc = fmaf(ev.w, sW[(kb + 3) * 64 + lane], acc);
        }
        float hv = softplus_f(acc) * w2;
#pragma unroll
        for (int off = 32; off > 0; off >>= 1) hv += __shfl_xor(hv, off, 64);
        if (lane == 0) sfm[n0 + sub] = hv + b2;
        __syncthreads();
    }

    if (tid < 3) {
        float s = 0.0f;
        for (int n = 0; n < 32; ++n)
            s += sfm[n] * unit[((size_t)atom * 32 + n) * 3 + tid];
        out[(size_t)atom * 3 + tid] = s;
    }
}

extern "C" void kernel_launch(void* const* d_in, const int* in_sizes, int n_in,
                              void* d_out, int out_size, void* d_ws, size_t ws_size,
                              hipStream_t stream) {
    const int*   Z    = (const int*)d_in[0];
    const int*   nbr  = (const int*)d_in[1];
    const float* dist = (const float*)d_in[2];
    const float* unit = (const float*)d_in[3];
    const float* emb  = (const float*)d_in[4];
    const float* Wnf  = (const float*)d_in[5];
    const float* bnf  = (const float*)d_in[6];
    const float* Wnc  = (const float*)d_in[7];
    const float* bnc  = (const float*)d_in[8];
    const float* Wef  = (const float*)d_in[9];
    const float* bef  = (const float*)d_in[10];
    const float* Wec  = (const float*)d_in[11];
    const float* bec  = (const float*)d_in[12];
    const float* Wo1  = (const float*)d_in[13];
    const float* bo1  = (const float*)d_in[14];
    const float* Wo2  = (const float*)d_in[15];
    const float* bo2  = (const float*)d_in[16];
    float* out = (float*)d_out;

    float* ws = (float*)d_ws;
    float* e   = ws;                               // NEDGE*FE          (64 MB)
    float* h0  = e + (size_t)NEDGE * FE;           // NA*FN
    float* h1  = h0 + (size_t)NA * FN;
    float* Pfi = h1 + (size_t)NA * FN;
    float* Pfj = Pfi + (size_t)NA * FN;
    float* Pci = Pfj + (size_t)NA * FN;
    float* Pcj = Pci + (size_t)NA * FN;

    k_init_h<<<(NA * FN) / 256, 256, 0, stream>>>(Z, emb, h0);
    k_init_e<<<(NEDGE * FE) / 256, 256, 0, stream>>>(dist, e);

    float* hc = h0;
    float* hn = h1;
    for (int l = 0; l < 3; ++l) {
        const float* wnf = Wnf + (size_t)l * WSTRIDE;
        const float* wnc = Wnc + (size_t)l * WSTRIDE;
        const float* wef = Wef + (size_t)l * WSTRIDE;
        const float* wec = Wec + (size_t)l * WSTRIDE;

        k_node_proj<<<NA / 16, 128, 0, stream>>>(hc, wnf, bnf + l * FN, Pfi, Pfj);
        k_node_proj<<<NA / 16, 128, 0, stream>>>(hc, wnc, bnc + l * FN, Pci, Pcj);
        k_node_update<<<NA, 512, 0, stream>>>(e, nbr, Pfi, Pfj, Pci, Pcj,
                                              wnf + EOFF, wnc + EOFF, hc, hn);
        k_node_proj<<<NA / 16, 128, 0, stream>>>(hn, wef, bef + l * FN, Pfi, Pfj);
        k_node_proj<<<NA / 16, 128, 0, stream>>>(hn, wec, bec + l * FN, Pci, Pcj);
        k_edge_update<<<NA, 512, 0, stream>>>(e, nbr, Pfi, Pfj, Pci, Pcj,
                                              wef + EOFF, wec + EOFF);
        float* t = hc; hc = hn; hn = t;
    }

    k_output<<<NA, 128, 0, stream>>>(e, Wo1, bo1, Wo2, bo2, unit, out);
}

// Round 3
// 1206.186 us; speedup vs baseline: 2.5724x; 2.5724x over previous
//
#include <hip/hip_runtime.h>
#include <math.h>

#define AT 1024
#define NBR 32
#define FN 128
#define FE 128
#define ZIN 384
#define NA 4096              // B*At
#define NEDGE (NA * NBR)     // 131072
#define WSTRIDE (ZIN * FN)   // 49152 floats per layer
#define EOFF (2 * FN * FN)   // 32768: offset of the e-part rows in W
#define G_ENDF 5.5f
#define WMAT 16384           // 128x128 elements per converted matrix

typedef unsigned short ushort_t;
typedef __attribute__((ext_vector_type(8))) short bf16x8;
typedef __attribute__((ext_vector_type(4))) float f32x4;

__device__ __forceinline__ float sigmoid_f(float x) {
    return 1.0f / (1.0f + expf(-x));
}
__device__ __forceinline__ float softplus_f(float x) {
    return fmaxf(x, 0.0f) + log1pf(expf(-fabsf(x)));
}
__device__ __forceinline__ ushort_t f2bf(float f) {
    unsigned int u = __float_as_uint(f);
    u = (u + 0x7FFFu + ((u >> 16) & 1u)) >> 16;   // RTNE
    return (ushort_t)u;
}
__device__ __forceinline__ float bf2f(ushort_t h) {
    return __uint_as_float(((unsigned int)h) << 16);
}

// -------- h0[atom][f] = emb[Z[atom]][f] --------
__global__ __launch_bounds__(256) void k_init_h(const int* __restrict__ Z,
                                                const float* __restrict__ emb,
                                                float* __restrict__ h) {
    int idx = blockIdx.x * 256 + threadIdx.x;
    int atom = idx >> 7, f = idx & 127;
    h[idx] = emb[Z[atom] * FN + f];
}

// -------- e[edge][f] = exp(coeff*(d - f*delta)^2) --------
__global__ __launch_bounds__(256) void k_init_e(const float* __restrict__ dist,
                                                float* __restrict__ e) {
    int idx = blockIdx.x * 256 + threadIdx.x;
    int edge = idx >> 7, f = idx & 127;
    const float delta = G_ENDF / 127.0f;
    const float coeff = -0.5f / (delta * delta);
    float d = dist[edge] - (float)f * delta;
    e[idx] = expf(coeff * d * d);
}

// -------- convert e-part weight blocks to split-bf16, transposed to [n][k] --------
// 12 matrices: w = l*4 + {0:Wnf, 1:Wnc, 2:Wef, 3:Wec}; hi and lo planes
__global__ __launch_bounds__(256) void k_conv_w(const float* __restrict__ Wnf,
                                                const float* __restrict__ Wnc,
                                                const float* __restrict__ Wef,
                                                const float* __restrict__ Wec,
                                                ushort_t* __restrict__ out_hi,
                                                ushort_t* __restrict__ out_lo) {
    int idx = blockIdx.x * 256 + threadIdx.x;   // over 12*16384
    int w = idx >> 14;
    int r = idx & 16383;
    int n = r >> 7, k = r & 127;
    int l = w >> 2, t = w & 3;
    const float* src = (t == 0 ? Wnf : t == 1 ? Wnc : t == 2 ? Wef : Wec)
                       + (size_t)l * WSTRIDE + EOFF;
    float x = src[k * 128 + n];
    ushort_t hi = f2bf(x);
    float lo = x - bf2f(hi);
    out_hi[idx] = hi;
    out_lo[idx] = f2bf(lo);
}

// -------- fused dual node projection (f32) --------
__global__ __launch_bounds__(128) void k_node_proj2(
    const float* __restrict__ h,
    const float* __restrict__ Wa, const float* __restrict__ ba,
    const float* __restrict__ Wb, const float* __restrict__ bb,
    float* __restrict__ Pai, float* __restrict__ Paj,
    float* __restrict__ Pbi, float* __restrict__ Pbj) {
    const int f = threadIdx.x;
    const int a0 = blockIdx.x * 16;
    __shared__ __align__(16) float sh[16 * 128];

    const float4* h4 = (const float4*)(h + (size_t)a0 * 128);
    float4* sh4 = (float4*)sh;
#pragma unroll
    for (int i = 0; i < 4; ++i) sh4[i * 128 + f] = h4[i * 128 + f];
    __syncthreads();

    float ai[16], aj[16], bi[16], bj[16];
    float bav = ba[f], bbv = bb[f];
#pragma unroll
    for (int a = 0; a < 16; ++a) { ai[a] = bav; aj[a] = 0.f; bi[a] = bbv; bj[a] = 0.f; }

#pragma unroll 2
    for (int k = 0; k < 128; ++k) {
        float wa0 = Wa[k * 128 + f];
        float wa1 = Wa[(128 + k) * 128 + f];
        float wb0 = Wb[k * 128 + f];
        float wb1 = Wb[(128 + k) * 128 + f];
#pragma unroll
        for (int a = 0; a < 16; ++a) {
            float hk = sh[a * 128 + k];
            ai[a] = fmaf(hk, wa0, ai[a]);
            aj[a] = fmaf(hk, wa1, aj[a]);
            bi[a] = fmaf(hk, wb0, bi[a]);
            bj[a] = fmaf(hk, wb1, bj[a]);
        }
    }
#pragma unroll
    for (int a = 0; a < 16; ++a) {
        Pai[(size_t)(a0 + a) * 128 + f] = ai[a];
        Paj[(size_t)(a0 + a) * 128 + f] = aj[a];
        Pbi[(size_t)(a0 + a) * 128 + f] = bi[a];
        Pbj[(size_t)(a0 + a) * 128 + f] = bj[a];
    }
}

// 3-term split-bf16 GEMM accumulate: acc += Ah*Bh + Ah*Bl + Al*Bh
__device__ __forceinline__ void gemm3(const ushort_t* sAh, const ushort_t* sAl,
                                      const ushort_t* sWh, const ushort_t* sWl,
                                      int wr, int wc, int lrow, int kgrp,
                                      f32x4 (&acc)[4][2]) {
#pragma unroll
    for (int kk = 0; kk < 4; ++kk) {
        const int kbase = kk * 32 + kgrp;
        bf16x8 ah[4], al[4], bh[2], bl[2];
#pragma unroll
        for (int mt = 0; mt < 4; ++mt) {
            ah[mt] = *(const bf16x8*)&sAh[(wr * 64 + mt * 16 + lrow) * 136 + kbase];
            al[mt] = *(const bf16x8*)&sAl[(wr * 64 + mt * 16 + lrow) * 136 + kbase];
        }
#pragma unroll
        for (int nt = 0; nt < 2; ++nt) {
            int nn = wc * 32 + nt * 16 + lrow;
            bh[nt] = *(const bf16x8*)&sWh[nn * 136 + kbase];
            bl[nt] = *(const bf16x8*)&sWl[nn * 136 + kbase];
        }
#pragma unroll
        for (int mt = 0; mt < 4; ++mt)
#pragma unroll
            for (int nt = 0; nt < 2; ++nt) {
                acc[mt][nt] = __builtin_amdgcn_mfma_f32_16x16x32_bf16(ah[mt], bh[nt], acc[mt][nt], 0, 0, 0);
                acc[mt][nt] = __builtin_amdgcn_mfma_f32_16x16x32_bf16(ah[mt], bl[nt], acc[mt][nt], 0, 0, 0);
                acc[mt][nt] = __builtin_amdgcn_mfma_f32_16x16x32_bf16(al[mt], bh[nt], acc[mt][nt], 0, 0, 0);
            }
    }
}

// -------- fused split-bf16 MFMA pass + epilogue --------
// block: 4 atoms = 128 edge rows, 512 threads = 8 waves (2 row-groups x 4 col-groups)
// NODE=1: h_new[atom] = h_old[atom] + sum_edges sigmoid(f)*softplus(c)
// NODE=0: e[edge] += sigmoid(f)*softplus(c)   (f32 residual path)
template <int NODE>
__global__ __launch_bounds__(512, 2) void k_pass(
    const float* __restrict__ e, float* __restrict__ e_out,
    const int* __restrict__ nbr,
    const float* __restrict__ Pfi, const float* __restrict__ Pfj,
    const float* __restrict__ Pci, const float* __restrict__ Pcj,
    const ushort_t* __restrict__ Wfh, const ushort_t* __restrict__ Wfl,
    const ushort_t* __restrict__ Wch, const ushort_t* __restrict__ Wcl,
    const float* __restrict__ h_old, float* __restrict__ h_new) {
    const int tid = threadIdx.x;
    const int a0 = blockIdx.x * 4;
    const int base = (a0 >> 10) << 10;

    __shared__ __align__(16) ushort_t sAh[128 * 136];
    __shared__ __align__(16) ushort_t sAl[128 * 136];
    __shared__ __align__(16) ushort_t sWh[128 * 136];
    __shared__ __align__(16) ushort_t sWl[128 * 136];
    __shared__ int snbr[128];

    // stage e -> split bf16 (row = tid>>2, 32 k per thread)
    {
        int row = tid >> 2;
        int kq = (tid & 3) * 32;
        const float4* src = (const float4*)(e + ((size_t)a0 * 32 + row) * 128 + kq);
        ushort_t* dh = &sAh[row * 136 + kq];
        ushort_t* dl = &sAl[row * 136 + kq];
#pragma unroll
        for (int i = 0; i < 8; ++i) {
            float4 v = src[i];
            ushort4 ph, pl;
            ph.x = f2bf(v.x); pl.x = f2bf(v.x - bf2f(ph.x));
            ph.y = f2bf(v.y); pl.y = f2bf(v.y - bf2f(ph.y));
            ph.z = f2bf(v.z); pl.z = f2bf(v.z - bf2f(ph.z));
            ph.w = f2bf(v.w); pl.w = f2bf(v.w - bf2f(ph.w));
            *(ushort4*)(dh + i * 4) = ph;
            *(ushort4*)(dl + i * 4) = pl;
        }
    }
    // stage Wf hi/lo: n = tid>>2, 32 k per thread
    {
        int n = tid >> 2;
        int kq = (tid & 3) * 32;
#pragma unroll
        for (int i = 0; i < 4; ++i) {
            *(uint4*)(&sWh[n * 136 + kq + i * 8]) = *(const uint4*)(Wfh + n * 128 + kq + i * 8);
            *(uint4*)(&sWl[n * 136 + kq + i * 8]) = *(const uint4*)(Wfl + n * 128 + kq + i * 8);
        }
    }
    if (tid < 128) snbr[tid] = nbr[a0 * 32 + tid];
    __syncthreads();

    const int w = tid >> 6;
    const int lane = tid & 63;
    const int wr = w >> 2;
    const int wc = w & 3;
    const int lrow = lane & 15;
    const int kgrp = (lane >> 4) * 8;

    f32x4 accf[4][2] = {};
    f32x4 accc[4][2] = {};

    gemm3(sAh, sAl, sWh, sWl, wr, wc, lrow, kgrp, accf);
    __syncthreads();

    // restage with Wc hi/lo
    {
        int n = tid >> 2;
        int kq = (tid & 3) * 32;
#pragma unroll
        for (int i = 0; i < 4; ++i) {
            *(uint4*)(&sWh[n * 136 + kq + i * 8]) = *(const uint4*)(Wch + n * 128 + kq + i * 8);
            *(uint4*)(&sWl[n * 136 + kq + i * 8]) = *(const uint4*)(Wcl + n * 128 + kq + i * 8);
        }
    }
    __syncthreads();

    gemm3(sAh, sAl, sWh, sWl, wr, wc, lrow, kgrp, accc);

    // epilogue. C layout: col = lane&15, row = (lane>>4)*4 + reg
    const int rbase4 = (lane >> 4) * 4;
    float hsum[2][2] = {{0.f, 0.f}, {0.f, 0.f}};

#pragma unroll
    for (int mt = 0; mt < 4; ++mt) {
        const int atom = a0 + ((wr * 64 + mt * 16) >> 5);
#pragma unroll
        for (int nt = 0; nt < 2; ++nt) {
            const int nn = wc * 32 + nt * 16 + lrow;
            const float pfi = Pfi[(size_t)atom * 128 + nn];
            const float pci = Pci[(size_t)atom * 128 + nn];
#pragma unroll
            for (int r = 0; r < 4; ++r) {
                const int rl = wr * 64 + mt * 16 + rbase4 + r;
                const int j = base + snbr[rl];
                float cf = accf[mt][nt][r] + pfi + Pfj[(size_t)j * 128 + nn];
                float cc = accc[mt][nt][r] + pci + Pcj[(size_t)j * 128 + nn];
                float msg = sigmoid_f(cf) * softplus_f(cc);
                if (NODE) {
                    hsum[mt >> 1][nt] += msg;
                } else {
                    size_t eoff = ((size_t)a0 * 32 + rl) * 128 + nn;
                    e_out[eoff] = e[eoff] + msg;
                }
            }
        }
    }

    if (NODE) {
#pragma unroll
        for (int at = 0; at < 2; ++at)
#pragma unroll
            for (int nt = 0; nt < 2; ++nt) {
                float v = hsum[at][nt];
                v += __shfl_xor(v, 16, 64);
                v += __shfl_xor(v, 32, 64);
                if (lane < 16) {
                    int atom = a0 + wr * 2 + at;
                    int nn = wc * 32 + nt * 16 + lane;
                    h_new[(size_t)atom * 128 + nn] =
                        h_old[(size_t)atom * 128 + nn] + v;
                }
            }
    }
}

// -------- output: fm = softplus(e@Wo1+bo1)@Wo2 + bo2 ; forces = sum_n fm*unit --------
__global__ __launch_bounds__(128) void k_output(
    const float* __restrict__ e, const float* __restrict__ Wo1,
    const float* __restrict__ bo1, const float* __restrict__ Wo2,
    const float* __restrict__ bo2, const float* __restrict__ unit,
    float* __restrict__ out) {
    const int tid = threadIdx.x;
    const int atom = blockIdx.x;
    const int lane = tid & 63;
    const int sub = tid >> 6;

    __shared__ __align__(16) float sW[128 * 64];
    __shared__ __align__(16) float se[2][128];
    __shared__ float sfm[32];

    {
        const float4* w4 = (const float4*)Wo1;
        float4* s4 = (float4*)sW;
#pragma unroll
        for (int i = 0; i < 16; ++i) s4[i * 128 + tid] = w4[i * 128 + tid];
    }
    const float b1 = bo1[lane];
    const float w2 = Wo2[lane];
    const float b2 = bo2[0];
    __syncthreads();

    for (int n0 = 0; n0 < 32; n0 += 2) {
        se[0][tid & 127] = e[((size_t)atom * 32 + n0) * 128 + (tid & 127)];
        se[1][tid & 127] = e[((size_t)atom * 32 + n0 + 1) * 128 + (tid & 127)];
        __syncthreads();

        float acc = b1;
        const float4* se4 = (const float4*)&se[sub][0];
#pragma unroll
        for (int kq = 0; kq < 32; ++kq) {
            float4 ev = se4[kq];
            int kb = kq * 4;
            acc = fmaf(ev.x, sW[(kb + 0) * 64 + lane], acc);
            acc = fmaf(ev.y, sW[(kb + 1) * 64 + lane], acc);
            acc = fmaf(ev.z, sW[(kb + 2) * 64 + lane], acc);
            acc = fmaf(ev.w, sW[(kb + 3) * 64 + lane], acc);
        }
        float hv = softplus_f(acc) * w2;
#pragma unroll
        for (int off = 32; off > 0; off >>= 1) hv += __shfl_xor(hv, off, 64);
        if (lane == 0) sfm[n0 + sub] = hv + b2;
        __syncthreads();
    }

    if (tid < 3) {
        float s = 0.0f;
        for (int n = 0; n < 32; ++n)
            s += sfm[n] * unit[((size_t)atom * 32 + n) * 3 + tid];
        out[(size_t)atom * 3 + tid] = s;
    }
}

extern "C" void kernel_launch(void* const* d_in, const int* in_sizes, int n_in,
                              void* d_out, int out_size, void* d_ws, size_t ws_size,
                              hipStream_t stream) {
    const int*   Z    = (const int*)d_in[0];
    const int*   nbr  = (const int*)d_in[1];
    const float* dist = (const float*)d_in[2];
    const float* unit = (const float*)d_in[3];
    const float* emb  = (const float*)d_in[4];
    const float* Wnf  = (const float*)d_in[5];
    const float* bnf  = (const float*)d_in[6];
    const float* Wnc  = (const float*)d_in[7];
    const float* bnc  = (const float*)d_in[8];
    const float* Wef  = (const float*)d_in[9];
    const float* bef  = (const float*)d_in[10];
    const float* Wec  = (const float*)d_in[11];
    const float* bec  = (const float*)d_in[12];
    const float* Wo1  = (const float*)d_in[13];
    const float* bo1  = (const float*)d_in[14];
    const float* Wo2  = (const float*)d_in[15];
    const float* bo2  = (const float*)d_in[16];
    float* out = (float*)d_out;

    float* ws = (float*)d_ws;
    float* e   = ws;                               // NEDGE*FE (64 MB)
    float* h0  = e + (size_t)NEDGE * FE;
    float* h1  = h0 + (size_t)NA * FN;
    float* Pfi = h1 + (size_t)NA * FN;
    float* Pfj = Pfi + (size_t)NA * FN;
    float* Pci = Pfj + (size_t)NA * FN;
    float* Pcj = Pci + (size_t)NA * FN;
    ushort_t* Whi = (ushort_t*)(Pcj + (size_t)NA * FN);  // 12 * 16384 bf16
    ushort_t* Wlo = Whi + (size_t)12 * WMAT;

    k_conv_w<<<(12 * WMAT) / 256, 256, 0, stream>>>(Wnf, Wnc, Wef, Wec, Whi, Wlo);
    k_init_h<<<(NA * FN) / 256, 256, 0, stream>>>(Z, emb, h0);
    k_init_e<<<(NEDGE * FE) / 256, 256, 0, stream>>>(dist, e);

    float* hc = h0;
    float* hn = h1;
    for (int l = 0; l < 3; ++l) {
        k_node_proj2<<<NA / 16, 128, 0, stream>>>(
            hc, Wnf + (size_t)l * WSTRIDE, bnf + l * FN,
            Wnc + (size_t)l * WSTRIDE, bnc + l * FN, Pfi, Pfj, Pci, Pcj);
        k_pass<1><<<NA / 4, 512, 0, stream>>>(
            e, e, nbr, Pfi, Pfj, Pci, Pcj,
            Whi + (size_t)(l * 4 + 0) * WMAT, Wlo + (size_t)(l * 4 + 0) * WMAT,
            Whi + (size_t)(l * 4 + 1) * WMAT, Wlo + (size_t)(l * 4 + 1) * WMAT,
            hc, hn);
        k_node_proj2<<<NA / 16, 128, 0, stream>>>(
            hn, Wef + (size_t)l * WSTRIDE, bef + l * FN,
            Wec + (size_t)l * WSTRIDE, bec + l * FN, Pfi, Pfj, Pci, Pcj);
        k_pass<0><<<NA / 4, 512, 0, stream>>>(
            e, e, nbr, Pfi, Pfj, Pci, Pcj,
            Whi + (size_t)(l * 4 + 2) * WMAT, Wlo + (size_t)(l * 4 + 2) * WMAT,
            Whi + (size_t)(l * 4 + 3) * WMAT, Wlo + (size_t)(l * 4 + 3) * WMAT,
            nullptr, nullptr);
        float* t = hc; hc = hn; hn = t;
    }

    k_output<<<NA, 128, 0, stream>>>(e, Wo1, bo1, Wo2, bo2, unit, out);
}

// Round 4
// 838.966 us; speedup vs baseline: 3.6984x; 1.4377x over previous
//
#include <hip/hip_runtime.h>
#include <math.h>

#define AT 1024
#define NBR 32
#define FN 128
#define FE 128
#define ZIN 384
#define NA 4096              // B*At
#define NEDGE (NA * NBR)     // 131072
#define WSTRIDE (ZIN * FN)   // 49152 floats per layer
#define G_ENDF 5.5f
#define WTMAT (384 * 128)    // converted matrix elements (transposed [n][k])
#define EPART (256 * 128)    // offset of e-part rows within converted matrix

typedef unsigned short ushort_t;
typedef __attribute__((ext_vector_type(8))) short bf16x8;
typedef __attribute__((ext_vector_type(4))) float f32x4;

__device__ __forceinline__ float sigmoid_f(float x) {
    return 1.0f / (1.0f + expf(-x));
}
__device__ __forceinline__ float softplus_f(float x) {
    return fmaxf(x, 0.0f) + log1pf(expf(-fabsf(x)));
}
__device__ __forceinline__ ushort_t f2bf(float f) {
    unsigned int u = __float_as_uint(f);
    u = (u + 0x7FFFu + ((u >> 16) & 1u)) >> 16;   // RTNE
    return (ushort_t)u;
}
__device__ __forceinline__ float bf2f(ushort_t h) {
    return __uint_as_float(((unsigned int)h) << 16);
}

// -------- h0[atom][f] = emb[Z[atom]][f] --------
__global__ __launch_bounds__(256) void k_init_h(const int* __restrict__ Z,
                                                const float* __restrict__ emb,
                                                float* __restrict__ h) {
    int idx = blockIdx.x * 256 + threadIdx.x;
    int atom = idx >> 7, f = idx & 127;
    h[idx] = emb[Z[atom] * FN + f];
}

// -------- convert all 12 weight matrices to split-bf16, transposed [n][k] --------
// Bt[n][k] = W[(n>>7)*128 + k][n&127];  n in [0,384): rows 0-255 = proj part,
// rows 256-383 = e part. grid = 12 mats x 3 parts, LDS-tiled transpose.
__global__ __launch_bounds__(256) void k_conv_w(const float* __restrict__ Wnf,
                                                const float* __restrict__ Wnc,
                                                const float* __restrict__ Wef,
                                                const float* __restrict__ Wec,
                                                ushort_t* __restrict__ Whi,
                                                ushort_t* __restrict__ Wlo) {
    const int blk = blockIdx.x;         // 0..35
    const int w = blk / 3, p = blk % 3;
    const int l = w >> 2, t = w & 3;
    const float* src = (t == 0 ? Wnf : t == 1 ? Wnc : t == 2 ? Wef : Wec)
                       + (size_t)l * WSTRIDE + (size_t)p * 128 * 128;
    __shared__ float tile[128][129];
    const int tid = threadIdx.x;
    {   // coalesced stage: thread loads half a row (64 floats)
        int k = tid >> 1, h = (tid & 1) * 64;
#pragma unroll
        for (int i = 0; i < 16; ++i) {
            float4 v = *(const float4*)&src[k * 128 + h + i * 4];
            tile[k][h + i * 4 + 0] = v.x; tile[k][h + i * 4 + 1] = v.y;
            tile[k][h + i * 4 + 2] = v.z; tile[k][h + i * 4 + 3] = v.w;
        }
    }
    __syncthreads();
    {   // transposed write: thread owns out-row f, half the k range
        int f = tid >> 1, kh = (tid & 1) * 64;
        size_t orow = (size_t)(w * 384 + p * 128 + f) * 128;
#pragma unroll
        for (int i = 0; i < 64; i += 4) {
            ushort4 ph, pl;
            float x0 = tile[kh + i + 0][f]; ph.x = f2bf(x0); pl.x = f2bf(x0 - bf2f(ph.x));
            float x1 = tile[kh + i + 1][f]; ph.y = f2bf(x1); pl.y = f2bf(x1 - bf2f(ph.y));
            float x2 = tile[kh + i + 2][f]; ph.z = f2bf(x2); pl.z = f2bf(x2 - bf2f(ph.z));
            float x3 = tile[kh + i + 3][f]; ph.w = f2bf(x3); pl.w = f2bf(x3 - bf2f(ph.w));
            *(ushort4*)&Whi[orow + kh + i] = ph;
            *(ushort4*)&Wlo[orow + kh + i] = pl;
        }
    }
}

// -------- Wo1 [128][64] -> Wo1t [64 n][128 k] split bf16 --------
__global__ __launch_bounds__(256) void k_conv_wo(const float* __restrict__ Wo1,
                                                 ushort_t* __restrict__ Wh,
                                                 ushort_t* __restrict__ Wl) {
    int idx = blockIdx.x * 256 + threadIdx.x;  // over 8192
    int n = idx >> 7, k = idx & 127;
    float x = Wo1[k * 64 + n];
    ushort_t h = f2bf(x);
    Wh[idx] = h;
    Wl[idx] = f2bf(x - bf2f(h));
}

// -------- MFMA projection: [Pai|Paj|Pbi|Pbj](4096x128 each) from h @ {Wa,Wb}[0:256] --------
// block = 16 atoms, 512 thr = 8 waves; wave w covers output cols w*64..+63 of the 512-wide C
__global__ __launch_bounds__(512, 4) void k_proj(
    const float* __restrict__ h,
    const ushort_t* __restrict__ Wah, const ushort_t* __restrict__ Wal,
    const ushort_t* __restrict__ Wbh, const ushort_t* __restrict__ Wbl,
    const float* __restrict__ ba, const float* __restrict__ bb,
    float* __restrict__ Pai, float* __restrict__ Paj,
    float* __restrict__ Pbi, float* __restrict__ Pbj) {
    const int tid = threadIdx.x;
    const int a0 = blockIdx.x * 16;
    __shared__ __align__(16) ushort_t sAh[16 * 136];
    __shared__ __align__(16) ushort_t sAl[16 * 136];
    {
        int row = tid >> 5, kq = (tid & 31) * 4;
        float4 v = *(const float4*)&h[(size_t)(a0 + row) * 128 + kq];
        ushort4 ph, pl;
        ph.x = f2bf(v.x); pl.x = f2bf(v.x - bf2f(ph.x));
        ph.y = f2bf(v.y); pl.y = f2bf(v.y - bf2f(ph.y));
        ph.z = f2bf(v.z); pl.z = f2bf(v.z - bf2f(ph.z));
        ph.w = f2bf(v.w); pl.w = f2bf(v.w - bf2f(ph.w));
        *(ushort4*)&sAh[row * 136 + kq] = ph;
        *(ushort4*)&sAl[row * 136 + kq] = pl;
    }
    __syncthreads();

    const int w = tid >> 6;
    const int lane = tid & 63;
    const int lrow = lane & 15;
    const int kgrp = (lane >> 4) * 8;

    f32x4 acc[4] = {};
#pragma unroll
    for (int kk = 0; kk < 4; ++kk) {
        const int kbase = kk * 32 + kgrp;
        bf16x8 ah = *(const bf16x8*)&sAh[lrow * 136 + kbase];
        bf16x8 al = *(const bf16x8*)&sAl[lrow * 136 + kbase];
#pragma unroll
        for (int nt = 0; nt < 4; ++nt) {
            int r512 = w * 64 + nt * 16 + lrow;
            const ushort_t* bh_p = (r512 < 256) ? (Wah + (size_t)r512 * 128)
                                                : (Wbh + (size_t)(r512 - 256) * 128);
            const ushort_t* bl_p = (r512 < 256) ? (Wal + (size_t)r512 * 128)
                                                : (Wbl + (size_t)(r512 - 256) * 128);
            bf16x8 bh = *(const bf16x8*)&bh_p[kbase];
            bf16x8 bl = *(const bf16x8*)&bl_p[kbase];
            acc[nt] = __builtin_amdgcn_mfma_f32_16x16x32_bf16(ah, bh, acc[nt], 0, 0, 0);
            acc[nt] = __builtin_amdgcn_mfma_f32_16x16x32_bf16(ah, bl, acc[nt], 0, 0, 0);
            acc[nt] = __builtin_amdgcn_mfma_f32_16x16x32_bf16(al, bh, acc[nt], 0, 0, 0);
        }
    }

    // epilogue: arr = w>>1 (0:Pai 1:Paj 2:Pbi 3:Pbj); f = (w&1)*64 + nt*16 + lrow
    const int arr = w >> 1;
    float* dst = (arr == 0) ? Pai : (arr == 1) ? Paj : (arr == 2) ? Pbi : Pbj;
    const int rb = (lane >> 4) * 4;
#pragma unroll
    for (int nt = 0; nt < 4; ++nt) {
        int f = (w & 1) * 64 + nt * 16 + lrow;
        float bs = (arr == 0) ? ba[f] : (arr == 2) ? bb[f] : 0.0f;
#pragma unroll
        for (int r = 0; r < 4; ++r) {
            int row = rb + r;
            dst[(size_t)(a0 + row) * 128 + f] = acc[nt][r] + bs;
        }
    }
}

// -------- fused split-bf16 MFMA pass --------
// block = 2 atoms = 64 edge rows, 512 thr = 8 waves (2 row-grp x 4 col-grp), W frags from global (L2)
// FIRST: generate e from dist (gaussian) + write e to global
// NODE=1: h_new = h_old + sum_n sigmoid(f)*softplus(c); NODE=0: e += ...
// FUSE (edge only): keep e_new on-chip, run output head, write forces
template <int NODE, int FIRST, int FUSE>
__global__ __launch_bounds__(512, 4) void k_pass(
    const float* __restrict__ e_g, float* __restrict__ e_out,
    const float* __restrict__ dist, const int* __restrict__ nbr,
    const float* __restrict__ Pfi, const float* __restrict__ Pfj,
    const float* __restrict__ Pci, const float* __restrict__ Pcj,
    const ushort_t* __restrict__ Wfh, const ushort_t* __restrict__ Wfl,
    const ushort_t* __restrict__ Wch, const ushort_t* __restrict__ Wcl,
    const float* __restrict__ h_old, float* __restrict__ h_new,
    const ushort_t* __restrict__ Wo1h, const ushort_t* __restrict__ Wo1l,
    const float* __restrict__ bo1, const float* __restrict__ Wo2,
    const float* __restrict__ bo2, const float* __restrict__ unit,
    float* __restrict__ out) {
    const int tid = threadIdx.x;
    const int a0 = blockIdx.x * 2;
    const int base = (a0 >> 10) << 10;

    __shared__ __align__(16) ushort_t sAh[64 * 136];
    __shared__ __align__(16) ushort_t sAl[64 * 136];
    __shared__ int snbr[64];
    __shared__ float sred[4][64];

    // ---- stage e (or generate from dist) -> split bf16 LDS ----
    {
        int row = tid >> 3, kq = (tid & 7) * 16;
        size_t eoff = ((size_t)(a0 * 32 + row)) * 128 + kq;
        float v[16];
        if (FIRST) {
            const float delta = G_ENDF / 127.0f;
            const float coeff = -0.5f / (delta * delta);
            float d = dist[a0 * 32 + row];
#pragma unroll
            for (int i = 0; i < 16; ++i) {
                float x = d - (float)(kq + i) * delta;
                v[i] = expf(coeff * x * x);
            }
#pragma unroll
            for (int i = 0; i < 4; ++i)
                *(float4*)&e_out[eoff + i * 4] =
                    make_float4(v[i * 4], v[i * 4 + 1], v[i * 4 + 2], v[i * 4 + 3]);
        } else {
#pragma unroll
            for (int i = 0; i < 4; ++i) {
                float4 t = *(const float4*)&e_g[eoff + i * 4];
                v[i * 4] = t.x; v[i * 4 + 1] = t.y; v[i * 4 + 2] = t.z; v[i * 4 + 3] = t.w;
            }
        }
#pragma unroll
        for (int i = 0; i < 4; ++i) {
            ushort4 ph, pl;
            ph.x = f2bf(v[i * 4 + 0]); pl.x = f2bf(v[i * 4 + 0] - bf2f(ph.x));
            ph.y = f2bf(v[i * 4 + 1]); pl.y = f2bf(v[i * 4 + 1] - bf2f(ph.y));
            ph.z = f2bf(v[i * 4 + 2]); pl.z = f2bf(v[i * 4 + 2] - bf2f(ph.z));
            ph.w = f2bf(v[i * 4 + 3]); pl.w = f2bf(v[i * 4 + 3] - bf2f(ph.w));
            *(ushort4*)&sAh[row * 136 + kq + i * 4] = ph;
            *(ushort4*)&sAl[row * 136 + kq + i * 4] = pl;
        }
    }
    if (tid < 64) snbr[tid] = nbr[a0 * 32 + tid];
    __syncthreads();

    const int w = tid >> 6;
    const int lane = tid & 63;
    const int wr = w >> 2;        // 0..1 : 32-row group = one atom
    const int wc = w & 3;         // 0..3 : 32-col group
    const int lrow = lane & 15;
    const int kgrp = (lane >> 4) * 8;
    const int rb = (lane >> 4) * 4;

    f32x4 accf[2][2] = {};
    f32x4 accc[2][2] = {};

#pragma unroll
    for (int kk = 0; kk < 4; ++kk) {
        const int kbase = kk * 32 + kgrp;
        bf16x8 ah[2], al[2];
#pragma unroll
        for (int mt = 0; mt < 2; ++mt) {
            ah[mt] = *(const bf16x8*)&sAh[(wr * 32 + mt * 16 + lrow) * 136 + kbase];
            al[mt] = *(const bf16x8*)&sAl[(wr * 32 + mt * 16 + lrow) * 136 + kbase];
        }
#pragma unroll
        for (int nt = 0; nt < 2; ++nt) {
            const int nn = wc * 32 + nt * 16 + lrow;
            bf16x8 bfh = *(const bf16x8*)&Wfh[(size_t)nn * 128 + kbase];
            bf16x8 bfl = *(const bf16x8*)&Wfl[(size_t)nn * 128 + kbase];
            bf16x8 bch = *(const bf16x8*)&Wch[(size_t)nn * 128 + kbase];
            bf16x8 bcl = *(const bf16x8*)&Wcl[(size_t)nn * 128 + kbase];
#pragma unroll
            for (int mt = 0; mt < 2; ++mt) {
                accf[mt][nt] = __builtin_amdgcn_mfma_f32_16x16x32_bf16(ah[mt], bfh, accf[mt][nt], 0, 0, 0);
                accf[mt][nt] = __builtin_amdgcn_mfma_f32_16x16x32_bf16(ah[mt], bfl, accf[mt][nt], 0, 0, 0);
                accf[mt][nt] = __builtin_amdgcn_mfma_f32_16x16x32_bf16(al[mt], bfh, accf[mt][nt], 0, 0, 0);
                accc[mt][nt] = __builtin_amdgcn_mfma_f32_16x16x32_bf16(ah[mt], bch, accc[mt][nt], 0, 0, 0);
                accc[mt][nt] = __builtin_amdgcn_mfma_f32_16x16x32_bf16(ah[mt], bcl, accc[mt][nt], 0, 0, 0);
                accc[mt][nt] = __builtin_amdgcn_mfma_f32_16x16x32_bf16(al[mt], bch, accc[mt][nt], 0, 0, 0);
            }
        }
    }

    if (FUSE) __syncthreads();   // all waves done reading A before we overwrite it

    // ---- epilogue ----
    float hsum[2] = {0.0f, 0.0f};
#pragma unroll
    for (int nt = 0; nt < 2; ++nt) {
        const int nn = wc * 32 + nt * 16 + lrow;
        const float pfi = Pfi[(size_t)(a0 + wr) * 128 + nn];
        const float pci = Pci[(size_t)(a0 + wr) * 128 + nn];
#pragma unroll
        for (int mt = 0; mt < 2; ++mt) {
#pragma unroll
            for (int r = 0; r < 4; ++r) {
                const int rl = wr * 32 + mt * 16 + rb + r;
                const int j = base + snbr[rl];
                float cf = accf[mt][nt][r] + pfi + Pfj[(size_t)j * 128 + nn];
                float cc = accc[mt][nt][r] + pci + Pcj[(size_t)j * 128 + nn];
                float msg = sigmoid_f(cf) * softplus_f(cc);
                if (NODE) {
                    hsum[nt] += msg;
                } else {
                    size_t eo = ((size_t)(a0 * 32 + rl)) * 128 + nn;
                    float enew = e_g[eo] + msg;
                    if (FUSE) {
                        ushort_t hh = f2bf(enew);
                        sAh[rl * 136 + nn] = hh;
                        sAl[rl * 136 + nn] = f2bf(enew - bf2f(hh));
                    } else {
                        e_out[eo] = enew;
                    }
                }
            }
        }
    }

    if (NODE) {
#pragma unroll
        for (int nt = 0; nt < 2; ++nt) {
            float v = hsum[nt];
            v += __shfl_xor(v, 16, 64);
            v += __shfl_xor(v, 32, 64);
            if (lane < 16) {
                int col = wc * 32 + nt * 16 + lane;
                h_new[(size_t)(a0 + wr) * 128 + col] =
                    h_old[(size_t)(a0 + wr) * 128 + col] + v;
            }
        }
    }

    if (FUSE) {
        __syncthreads();   // e_new fully in LDS
        // output head: C2 = e_new @ Wo1t^T  (64 rows x 64 cols), wave: rows wr*32..+31, cols wc*16..+15
        f32x4 acco[2] = {};
        const int col = wc * 16 + lrow;
#pragma unroll
        for (int kk = 0; kk < 4; ++kk) {
            const int kbase = kk * 32 + kgrp;
            bf16x8 bh = *(const bf16x8*)&Wo1h[(size_t)col * 128 + kbase];
            bf16x8 bl = *(const bf16x8*)&Wo1l[(size_t)col * 128 + kbase];
#pragma unroll
            for (int mt = 0; mt < 2; ++mt) {
                bf16x8 ah = *(const bf16x8*)&sAh[(wr * 32 + mt * 16 + lrow) * 136 + kbase];
                bf16x8 al = *(const bf16x8*)&sAl[(wr * 32 + mt * 16 + lrow) * 136 + kbase];
                acco[mt] = __builtin_amdgcn_mfma_f32_16x16x32_bf16(ah, bh, acco[mt], 0, 0, 0);
                acco[mt] = __builtin_amdgcn_mfma_f32_16x16x32_bf16(ah, bl, acco[mt], 0, 0, 0);
                acco[mt] = __builtin_amdgcn_mfma_f32_16x16x32_bf16(al, bh, acco[mt], 0, 0, 0);
            }
        }
        const float b1 = bo1[col];
        const float w2 = Wo2[col];
#pragma unroll
        for (int mt = 0; mt < 2; ++mt) {
#pragma unroll
            for (int r = 0; r < 4; ++r) {
                float val = softplus_f(acco[mt][r] + b1) * w2;
                val += __shfl_xor(val, 1, 64);
                val += __shfl_xor(val, 2, 64);
                val += __shfl_xor(val, 4, 64);
                val += __shfl_xor(val, 8, 64);
                if (lrow == 0) sred[wc][wr * 32 + mt * 16 + rb + r] = val;
            }
        }
        __syncthreads();
        if (tid < 6) {
            int a = (tid < 3) ? 0 : 1;
            int c = tid - a * 3;
            float b2 = bo2[0];
            float s = 0.0f;
#pragma unroll 4
            for (int n = 0; n < 32; ++n) {
                int row = a * 32 + n;
                float fm = sred[0][row] + sred[1][row] + sred[2][row] + sred[3][row] + b2;
                s += fm * unit[((size_t)((a0 + a) * 32 + n)) * 3 + c];
            }
            out[(size_t)(a0 + a) * 3 + c] = s;
        }
    }
}

extern "C" void kernel_launch(void* const* d_in, const int* in_sizes, int n_in,
                              void* d_out, int out_size, void* d_ws, size_t ws_size,
                              hipStream_t stream) {
    const int*   Z    = (const int*)d_in[0];
    const int*   nbr  = (const int*)d_in[1];
    const float* dist = (const float*)d_in[2];
    const float* unit = (const float*)d_in[3];
    const float* emb  = (const float*)d_in[4];
    const float* Wnf  = (const float*)d_in[5];
    const float* bnf  = (const float*)d_in[6];
    const float* Wnc  = (const float*)d_in[7];
    const float* bnc  = (const float*)d_in[8];
    const float* Wef  = (const float*)d_in[9];
    const float* bef  = (const float*)d_in[10];
    const float* Wec  = (const float*)d_in[11];
    const float* bec  = (const float*)d_in[12];
    const float* Wo1  = (const float*)d_in[13];
    const float* bo1  = (const float*)d_in[14];
    const float* Wo2  = (const float*)d_in[15];
    const float* bo2  = (const float*)d_in[16];
    float* out = (float*)d_out;

    float* ws = (float*)d_ws;
    float* e   = ws;                               // NEDGE*FE (67 MB)
    float* h0  = e + (size_t)NEDGE * FE;
    float* h1  = h0 + (size_t)NA * FN;
    float* Pfi = h1 + (size_t)NA * FN;
    float* Pfj = Pfi + (size_t)NA * FN;
    float* Pci = Pfj + (size_t)NA * FN;
    float* Pcj = Pci + (size_t)NA * FN;
    ushort_t* Whi  = (ushort_t*)(Pcj + (size_t)NA * FN);   // 12 * 384*128
    ushort_t* Wlo  = Whi + (size_t)12 * WTMAT;
    ushort_t* Wo1h = Wlo + (size_t)12 * WTMAT;             // 64*128
    ushort_t* Wo1l = Wo1h + (size_t)64 * 128;

    k_conv_w<<<36, 256, 0, stream>>>(Wnf, Wnc, Wef, Wec, Whi, Wlo);
    k_conv_wo<<<32, 256, 0, stream>>>(Wo1, Wo1h, Wo1l);
    k_init_h<<<(NA * FN) / 256, 256, 0, stream>>>(Z, emb, h0);

    float* hc = h0;
    float* hn = h1;
    for (int l = 0; l < 3; ++l) {
        const ushort_t* nf_h = Whi + (size_t)(l * 4 + 0) * WTMAT;
        const ushort_t* nf_l = Wlo + (size_t)(l * 4 + 0) * WTMAT;
        const ushort_t* nc_h = Whi + (size_t)(l * 4 + 1) * WTMAT;
        const ushort_t* nc_l = Wlo + (size_t)(l * 4 + 1) * WTMAT;
        const ushort_t* ef_h = Whi + (size_t)(l * 4 + 2) * WTMAT;
        const ushort_t* ef_l = Wlo + (size_t)(l * 4 + 2) * WTMAT;
        const ushort_t* ec_h = Whi + (size_t)(l * 4 + 3) * WTMAT;
        const ushort_t* ec_l = Wlo + (size_t)(l * 4 + 3) * WTMAT;

        // node stage
        k_proj<<<NA / 16, 512, 0, stream>>>(hc, nf_h, nf_l, nc_h, nc_l,
                                            bnf + l * FN, bnc + l * FN,
                                            Pfi, Pfj, Pci, Pcj);
        if (l == 0)
            k_pass<1, 1, 0><<<NA / 2, 512, 0, stream>>>(
                e, e, dist, nbr, Pfi, Pfj, Pci, Pcj,
                nf_h + EPART, nf_l + EPART, nc_h + EPART, nc_l + EPART,
                hc, hn, nullptr, nullptr, nullptr, nullptr, nullptr, nullptr, nullptr);
        else
            k_pass<1, 0, 0><<<NA / 2, 512, 0, stream>>>(
                e, e, dist, nbr, Pfi, Pfj, Pci, Pcj,
                nf_h + EPART, nf_l + EPART, nc_h + EPART, nc_l + EPART,
                hc, hn, nullptr, nullptr, nullptr, nullptr, nullptr, nullptr, nullptr);

        // edge stage
        k_proj<<<NA / 16, 512, 0, stream>>>(hn, ef_h, ef_l, ec_h, ec_l,
                                            bef + l * FN, bec + l * FN,
                                            Pfi, Pfj, Pci, Pcj);
        if (l < 2)
            k_pass<0, 0, 0><<<NA / 2, 512, 0, stream>>>(
                e, e, dist, nbr, Pfi, Pfj, Pci, Pcj,
                ef_h + EPART, ef_l + EPART, ec_h + EPART, ec_l + EPART,
                nullptr, nullptr, nullptr, nullptr, nullptr, nullptr, nullptr, nullptr, nullptr);
        else
            k_pass<0, 0, 1><<<NA / 2, 512, 0, stream>>>(
                e, e, dist, nbr, Pfi, Pfj, Pci, Pcj,
                ef_h + EPART, ef_l + EPART, ec_h + EPART, ec_l + EPART,
                nullptr, nullptr, Wo1h, Wo1l, bo1, Wo2, bo2, unit, out);

        float* t = hc; hc = hn; hn = t;
    }
}

// Round 5
// 678.114 us; speedup vs baseline: 4.5756x; 1.2372x over previous
//
#include <hip/hip_runtime.h>
#include <math.h>

#define AT 1024
#define NBR 32
#define FN 128
#define FE 128
#define ZIN 384
#define NA 4096              // B*At
#define NEDGE (NA * NBR)     // 131072
#define WSTRIDE (ZIN * FN)   // 49152 floats per layer
#define G_ENDF 5.5f
#define WTMAT (384 * 128)    // converted matrix elements (transposed [n][k])
#define EPART (256 * 128)    // offset of e-part rows within converted matrix

typedef unsigned short ushort_t;
typedef __attribute__((ext_vector_type(8))) short bf16x8;
typedef __attribute__((ext_vector_type(4))) float f32x4;

#define LOG2E 1.4426950408889634f
#define LN2   0.6931471805599453f

// native-instruction transcendentals (v_exp_f32 / v_log_f32 / v_rcp_f32, ~1 ulp)
__device__ __forceinline__ float fexp(float x) {
    return __builtin_amdgcn_exp2f(x * LOG2E);
}
__device__ __forceinline__ float sigmoid_f(float x) {
    return __builtin_amdgcn_rcpf(1.0f + __builtin_amdgcn_exp2f(-x * LOG2E));
}
__device__ __forceinline__ float softplus_f(float x) {
    float t = __builtin_amdgcn_exp2f(-fabsf(x) * LOG2E);
    return fmaxf(x, 0.0f) + LN2 * __builtin_amdgcn_logf(1.0f + t);
}

__device__ __forceinline__ ushort_t f2bf(float f) {
    unsigned int u = __float_as_uint(f);
    u = (u + 0x7FFFu + ((u >> 16) & 1u)) >> 16;   // RTNE
    return (ushort_t)u;
}
__device__ __forceinline__ float bf2f(ushort_t h) {
    return __uint_as_float(((unsigned int)h) << 16);
}
// packed 2xfloat -> 2xbf16 in one instruction (RTNE)
__device__ __forceinline__ unsigned int cvt_pk_bf16(float a, float b) {
    unsigned int r;
    asm("v_cvt_pk_bf16_f32 %0, %1, %2" : "=v"(r) : "v"(a), "v"(b));
    return r;
}
// split-bf16 of a float pair: hi word-pair + lo word-pair
__device__ __forceinline__ void split2(float a, float b,
                                       unsigned int& hi, unsigned int& lo) {
    hi = cvt_pk_bf16(a, b);
    float ha = __uint_as_float(hi << 16);
    float hb = __uint_as_float(hi & 0xffff0000u);
    lo = cvt_pk_bf16(a - ha, b - hb);
}

// -------- h0[atom][f] = emb[Z[atom]][f] --------
__global__ __launch_bounds__(256) void k_init_h(const int* __restrict__ Z,
                                                const float* __restrict__ emb,
                                                float* __restrict__ h) {
    int idx = blockIdx.x * 256 + threadIdx.x;
    int atom = idx >> 7, f = idx & 127;
    h[idx] = emb[Z[atom] * FN + f];
}

// -------- convert all 12 weight matrices to split-bf16, transposed [n][k] --------
__global__ __launch_bounds__(256) void k_conv_w(const float* __restrict__ Wnf,
                                                const float* __restrict__ Wnc,
                                                const float* __restrict__ Wef,
                                                const float* __restrict__ Wec,
                                                ushort_t* __restrict__ Whi,
                                                ushort_t* __restrict__ Wlo) {
    const int blk = blockIdx.x;         // 0..35
    const int w = blk / 3, p = blk % 3;
    const int l = w >> 2, t = w & 3;
    const float* src = (t == 0 ? Wnf : t == 1 ? Wnc : t == 2 ? Wef : Wec)
                       + (size_t)l * WSTRIDE + (size_t)p * 128 * 128;
    __shared__ float tile[128][129];
    const int tid = threadIdx.x;
    {
        int k = tid >> 1, h = (tid & 1) * 64;
#pragma unroll
        for (int i = 0; i < 16; ++i) {
            float4 v = *(const float4*)&src[k * 128 + h + i * 4];
            tile[k][h + i * 4 + 0] = v.x; tile[k][h + i * 4 + 1] = v.y;
            tile[k][h + i * 4 + 2] = v.z; tile[k][h + i * 4 + 3] = v.w;
        }
    }
    __syncthreads();
    {
        int f = tid >> 1, kh = (tid & 1) * 64;
        size_t orow = (size_t)(w * 384 + p * 128 + f) * 128;
#pragma unroll
        for (int i = 0; i < 64; i += 4) {
            ushort4 ph, pl;
            float x0 = tile[kh + i + 0][f]; ph.x = f2bf(x0); pl.x = f2bf(x0 - bf2f(ph.x));
            float x1 = tile[kh + i + 1][f]; ph.y = f2bf(x1); pl.y = f2bf(x1 - bf2f(ph.y));
            float x2 = tile[kh + i + 2][f]; ph.z = f2bf(x2); pl.z = f2bf(x2 - bf2f(ph.z));
            float x3 = tile[kh + i + 3][f]; ph.w = f2bf(x3); pl.w = f2bf(x3 - bf2f(ph.w));
            *(ushort4*)&Whi[orow + kh + i] = ph;
            *(ushort4*)&Wlo[orow + kh + i] = pl;
        }
    }
}

// -------- Wo1 [128][64] -> Wo1t [64 n][128 k] split bf16 --------
__global__ __launch_bounds__(256) void k_conv_wo(const float* __restrict__ Wo1,
                                                 ushort_t* __restrict__ Wh,
                                                 ushort_t* __restrict__ Wl) {
    int idx = blockIdx.x * 256 + threadIdx.x;  // over 8192
    int n = idx >> 7, k = idx & 127;
    float x = Wo1[k * 64 + n];
    ushort_t h = f2bf(x);
    Wh[idx] = h;
    Wl[idx] = f2bf(x - bf2f(h));
}

// -------- MFMA projection: [Pai|Paj|Pbi|Pbj](4096x128 each) from h @ {Wa,Wb}[0:256] --------
__global__ __launch_bounds__(512, 4) void k_proj(
    const float* __restrict__ h,
    const ushort_t* __restrict__ Wah, const ushort_t* __restrict__ Wal,
    const ushort_t* __restrict__ Wbh, const ushort_t* __restrict__ Wbl,
    const float* __restrict__ ba, const float* __restrict__ bb,
    float* __restrict__ Pai, float* __restrict__ Paj,
    float* __restrict__ Pbi, float* __restrict__ Pbj) {
    const int tid = threadIdx.x;
    const int a0 = blockIdx.x * 16;
    __shared__ __align__(16) ushort_t sAh[16 * 136];
    __shared__ __align__(16) ushort_t sAl[16 * 136];
    {
        int row = tid >> 5, kq = (tid & 31) * 4;
        float4 v = *(const float4*)&h[(size_t)(a0 + row) * 128 + kq];
        unsigned int h0, l0, h1, l1;
        split2(v.x, v.y, h0, l0);
        split2(v.z, v.w, h1, l1);
        *(uint2*)&sAh[row * 136 + kq] = make_uint2(h0, h1);
        *(uint2*)&sAl[row * 136 + kq] = make_uint2(l0, l1);
    }
    __syncthreads();

    const int w = tid >> 6;
    const int lane = tid & 63;
    const int lrow = lane & 15;
    const int kgrp = (lane >> 4) * 8;

    f32x4 acc[4] = {};
#pragma unroll
    for (int kk = 0; kk < 4; ++kk) {
        const int kbase = kk * 32 + kgrp;
        bf16x8 ah = *(const bf16x8*)&sAh[lrow * 136 + kbase];
        bf16x8 al = *(const bf16x8*)&sAl[lrow * 136 + kbase];
#pragma unroll
        for (int nt = 0; nt < 4; ++nt) {
            int r512 = w * 64 + nt * 16 + lrow;
            const ushort_t* bh_p = (r512 < 256) ? (Wah + (size_t)r512 * 128)
                                                : (Wbh + (size_t)(r512 - 256) * 128);
            const ushort_t* bl_p = (r512 < 256) ? (Wal + (size_t)r512 * 128)
                                                : (Wbl + (size_t)(r512 - 256) * 128);
            bf16x8 bh = *(const bf16x8*)&bh_p[kbase];
            bf16x8 bl = *(const bf16x8*)&bl_p[kbase];
            acc[nt] = __builtin_amdgcn_mfma_f32_16x16x32_bf16(ah, bh, acc[nt], 0, 0, 0);
            acc[nt] = __builtin_amdgcn_mfma_f32_16x16x32_bf16(ah, bl, acc[nt], 0, 0, 0);
            acc[nt] = __builtin_amdgcn_mfma_f32_16x16x32_bf16(al, bh, acc[nt], 0, 0, 0);
        }
    }

    const int arr = w >> 1;
    float* dst = (arr == 0) ? Pai : (arr == 1) ? Paj : (arr == 2) ? Pbi : Pbj;
    const int rb = (lane >> 4) * 4;
#pragma unroll
    for (int nt = 0; nt < 4; ++nt) {
        int f = (w & 1) * 64 + nt * 16 + lrow;
        float bs = (arr == 0) ? ba[f] : (arr == 2) ? bb[f] : 0.0f;
#pragma unroll
        for (int r = 0; r < 4; ++r) {
            int row = rb + r;
            dst[(size_t)(a0 + row) * 128 + f] = acc[nt][r] + bs;
        }
    }
}

// -------- fused split-bf16 MFMA pass --------
template <int NODE, int FIRST, int FUSE>
__global__ __launch_bounds__(512, 4) void k_pass(
    const float* __restrict__ e_g, float* __restrict__ e_out,
    const float* __restrict__ dist, const int* __restrict__ nbr,
    const float* __restrict__ Pfi, const float* __restrict__ Pfj,
    const float* __restrict__ Pci, const float* __restrict__ Pcj,
    const ushort_t* __restrict__ Wfh, const ushort_t* __restrict__ Wfl,
    const ushort_t* __restrict__ Wch, const ushort_t* __restrict__ Wcl,
    const float* __restrict__ h_old, float* __restrict__ h_new,
    const ushort_t* __restrict__ Wo1h, const ushort_t* __restrict__ Wo1l,
    const float* __restrict__ bo1, const float* __restrict__ Wo2,
    const float* __restrict__ bo2, const float* __restrict__ unit,
    float* __restrict__ out) {
    const int tid = threadIdx.x;
    const int a0 = blockIdx.x * 2;
    const int base = (a0 >> 10) << 10;

    __shared__ __align__(16) ushort_t sAh[64 * 136];
    __shared__ __align__(16) ushort_t sAl[64 * 136];
    __shared__ int snbr[64];
    __shared__ float sred[4][64];

    // ---- stage e (or generate from dist) -> split bf16 LDS ----
    {
        int row = tid >> 3, kq = (tid & 7) * 16;
        size_t eoff = ((size_t)(a0 * 32 + row)) * 128 + kq;
        float v[16];
        if (FIRST) {
            const float delta = G_ENDF / 127.0f;
            const float coeff = -0.5f / (delta * delta);
            float d = dist[a0 * 32 + row];
#pragma unroll
            for (int i = 0; i < 16; ++i) {
                float x = d - (float)(kq + i) * delta;
                v[i] = fexp(coeff * x * x);
            }
#pragma unroll
            for (int i = 0; i < 4; ++i)
                *(float4*)&e_out[eoff + i * 4] =
                    make_float4(v[i * 4], v[i * 4 + 1], v[i * 4 + 2], v[i * 4 + 3]);
        } else {
#pragma unroll
            for (int i = 0; i < 4; ++i) {
                float4 t = *(const float4*)&e_g[eoff + i * 4];
                v[i * 4] = t.x; v[i * 4 + 1] = t.y; v[i * 4 + 2] = t.z; v[i * 4 + 3] = t.w;
            }
        }
#pragma unroll
        for (int i = 0; i < 4; ++i) {
            unsigned int h0, l0, h1, l1;
            split2(v[i * 4 + 0], v[i * 4 + 1], h0, l0);
            split2(v[i * 4 + 2], v[i * 4 + 3], h1, l1);
            *(uint2*)&sAh[row * 136 + kq + i * 4] = make_uint2(h0, h1);
            *(uint2*)&sAl[row * 136 + kq + i * 4] = make_uint2(l0, l1);
        }
    }
    if (tid < 64) snbr[tid] = nbr[a0 * 32 + tid];
    __syncthreads();

    const int w = tid >> 6;
    const int lane = tid & 63;
    const int wr = w >> 2;        // 0..1 : 32-row group = one atom
    const int wc = w & 3;         // 0..3 : 32-col group
    const int lrow = lane & 15;
    const int kgrp = (lane >> 4) * 8;
    const int rb = (lane >> 4) * 4;

    f32x4 accf[2][2] = {};
    f32x4 accc[2][2] = {};

#pragma unroll
    for (int kk = 0; kk < 4; ++kk) {
        const int kbase = kk * 32 + kgrp;
        bf16x8 ah[2], al[2];
#pragma unroll
        for (int mt = 0; mt < 2; ++mt) {
            ah[mt] = *(const bf16x8*)&sAh[(wr * 32 + mt * 16 + lrow) * 136 + kbase];
            al[mt] = *(const bf16x8*)&sAl[(wr * 32 + mt * 16 + lrow) * 136 + kbase];
        }
#pragma unroll
        for (int nt = 0; nt < 2; ++nt) {
            const int nn = wc * 32 + nt * 16 + lrow;
            bf16x8 bfh = *(const bf16x8*)&Wfh[(size_t)nn * 128 + kbase];
            bf16x8 bfl = *(const bf16x8*)&Wfl[(size_t)nn * 128 + kbase];
            bf16x8 bch = *(const bf16x8*)&Wch[(size_t)nn * 128 + kbase];
            bf16x8 bcl = *(const bf16x8*)&Wcl[(size_t)nn * 128 + kbase];
#pragma unroll
            for (int mt = 0; mt < 2; ++mt) {
                accf[mt][nt] = __builtin_amdgcn_mfma_f32_16x16x32_bf16(ah[mt], bfh, accf[mt][nt], 0, 0, 0);
                accf[mt][nt] = __builtin_amdgcn_mfma_f32_16x16x32_bf16(ah[mt], bfl, accf[mt][nt], 0, 0, 0);
                accf[mt][nt] = __builtin_amdgcn_mfma_f32_16x16x32_bf16(al[mt], bfh, accf[mt][nt], 0, 0, 0);
                accc[mt][nt] = __builtin_amdgcn_mfma_f32_16x16x32_bf16(ah[mt], bch, accc[mt][nt], 0, 0, 0);
                accc[mt][nt] = __builtin_amdgcn_mfma_f32_16x16x32_bf16(ah[mt], bcl, accc[mt][nt], 0, 0, 0);
                accc[mt][nt] = __builtin_amdgcn_mfma_f32_16x16x32_bf16(al[mt], bch, accc[mt][nt], 0, 0, 0);
            }
        }
    }

    if (FUSE) __syncthreads();   // all waves done reading A before we overwrite it

    // ---- epilogue ----
    float hsum[2] = {0.0f, 0.0f};
#pragma unroll
    for (int nt = 0; nt < 2; ++nt) {
        const int nn = wc * 32 + nt * 16 + lrow;
        const float pfi = Pfi[(size_t)(a0 + wr) * 128 + nn];
        const float pci = Pci[(size_t)(a0 + wr) * 128 + nn];
#pragma unroll
        for (int mt = 0; mt < 2; ++mt) {
#pragma unroll
            for (int r = 0; r < 4; ++r) {
                const int rl = wr * 32 + mt * 16 + rb + r;
                const int j = base + snbr[rl];
                float cf = accf[mt][nt][r] + pfi + Pfj[(size_t)j * 128 + nn];
                float cc = accc[mt][nt][r] + pci + Pcj[(size_t)j * 128 + nn];
                float msg = sigmoid_f(cf) * softplus_f(cc);
                if (NODE) {
                    hsum[nt] += msg;
                } else {
                    size_t eo = ((size_t)(a0 * 32 + rl)) * 128 + nn;
                    float enew = e_g[eo] + msg;
                    if (FUSE) {
                        ushort_t hh = f2bf(enew);
                        sAh[rl * 136 + nn] = hh;
                        sAl[rl * 136 + nn] = f2bf(enew - bf2f(hh));
                    } else {
                        e_out[eo] = enew;
                    }
                }
            }
        }
    }

    if (NODE) {
#pragma unroll
        for (int nt = 0; nt < 2; ++nt) {
            float v = hsum[nt];
            v += __shfl_xor(v, 16, 64);
            v += __shfl_xor(v, 32, 64);
            if (lane < 16) {
                int col = wc * 32 + nt * 16 + lane;
                h_new[(size_t)(a0 + wr) * 128 + col] =
                    h_old[(size_t)(a0 + wr) * 128 + col] + v;
            }
        }
    }

    if (FUSE) {
        __syncthreads();   // e_new fully in LDS
        f32x4 acco[2] = {};
        const int col = wc * 16 + lrow;
#pragma unroll
        for (int kk = 0; kk < 4; ++kk) {
            const int kbase = kk * 32 + kgrp;
            bf16x8 bh = *(const bf16x8*)&Wo1h[(size_t)col * 128 + kbase];
            bf16x8 bl = *(const bf16x8*)&Wo1l[(size_t)col * 128 + kbase];
#pragma unroll
            for (int mt = 0; mt < 2; ++mt) {
                bf16x8 ah = *(const bf16x8*)&sAh[(wr * 32 + mt * 16 + lrow) * 136 + kbase];
                bf16x8 al = *(const bf16x8*)&sAl[(wr * 32 + mt * 16 + lrow) * 136 + kbase];
                acco[mt] = __builtin_amdgcn_mfma_f32_16x16x32_bf16(ah, bh, acco[mt], 0, 0, 0);
                acco[mt] = __builtin_amdgcn_mfma_f32_16x16x32_bf16(ah, bl, acco[mt], 0, 0, 0);
                acco[mt] = __builtin_amdgcn_mfma_f32_16x16x32_bf16(al, bh, acco[mt], 0, 0, 0);
            }
        }
        const float b1 = bo1[col];
        const float w2 = Wo2[col];
#pragma unroll
        for (int mt = 0; mt < 2; ++mt) {
#pragma unroll
            for (int r = 0; r < 4; ++r) {
                float val = softplus_f(acco[mt][r] + b1) * w2;
                val += __shfl_xor(val, 1, 64);
                val += __shfl_xor(val, 2, 64);
                val += __shfl_xor(val, 4, 64);
                val += __shfl_xor(val, 8, 64);
                if (lrow == 0) sred[wc][wr * 32 + mt * 16 + rb + r] = val;
            }
        }
        __syncthreads();
        if (tid < 6) {
            int a = (tid < 3) ? 0 : 1;
            int c = tid - a * 3;
            float b2 = bo2[0];
            float s = 0.0f;
#pragma unroll 4
            for (int n = 0; n < 32; ++n) {
                int row = a * 32 + n;
                float fm = sred[0][row] + sred[1][row] + sred[2][row] + sred[3][row] + b2;
                s += fm * unit[((size_t)((a0 + a) * 32 + n)) * 3 + c];
            }
            out[(size_t)(a0 + a) * 3 + c] = s;
        }
    }
}

extern "C" void kernel_launch(void* const* d_in, const int* in_sizes, int n_in,
                              void* d_out, int out_size, void* d_ws, size_t ws_size,
                              hipStream_t stream) {
    const int*   Z    = (const int*)d_in[0];
    const int*   nbr  = (const int*)d_in[1];
    const float* dist = (const float*)d_in[2];
    const float* unit = (const float*)d_in[3];
    const float* emb  = (const float*)d_in[4];
    const float* Wnf  = (const float*)d_in[5];
    const float* bnf  = (const float*)d_in[6];
    const float* Wnc  = (const float*)d_in[7];
    const float* bnc  = (const float*)d_in[8];
    const float* Wef  = (const float*)d_in[9];
    const float* bef  = (const float*)d_in[10];
    const float* Wec  = (const float*)d_in[11];
    const float* bec  = (const float*)d_in[12];
    const float* Wo1  = (const float*)d_in[13];
    const float* bo1  = (const float*)d_in[14];
    const float* Wo2  = (const float*)d_in[15];
    const float* bo2  = (const float*)d_in[16];
    float* out = (float*)d_out;

    float* ws = (float*)d_ws;
    float* e   = ws;                               // NEDGE*FE (67 MB)
    float* h0  = e + (size_t)NEDGE * FE;
    float* h1  = h0 + (size_t)NA * FN;
    float* Pfi = h1 + (size_t)NA * FN;
    float* Pfj = Pfi + (size_t)NA * FN;
    float* Pci = Pfj + (size_t)NA * FN;
    float* Pcj = Pci + (size_t)NA * FN;
    ushort_t* Whi  = (ushort_t*)(Pcj + (size_t)NA * FN);   // 12 * 384*128
    ushort_t* Wlo  = Whi + (size_t)12 * WTMAT;
    ushort_t* Wo1h = Wlo + (size_t)12 * WTMAT;             // 64*128
    ushort_t* Wo1l = Wo1h + (size_t)64 * 128;

    k_conv_w<<<36, 256, 0, stream>>>(Wnf, Wnc, Wef, Wec, Whi, Wlo);
    k_conv_wo<<<32, 256, 0, stream>>>(Wo1, Wo1h, Wo1l);
    k_init_h<<<(NA * FN) / 256, 256, 0, stream>>>(Z, emb, h0);

    float* hc = h0;
    float* hn = h1;
    for (int l = 0; l < 3; ++l) {
        const ushort_t* nf_h = Whi + (size_t)(l * 4 + 0) * WTMAT;
        const ushort_t* nf_l = Wlo + (size_t)(l * 4 + 0) * WTMAT;
        const ushort_t* nc_h = Whi + (size_t)(l * 4 + 1) * WTMAT;
        const ushort_t* nc_l = Wlo + (size_t)(l * 4 + 1) * WTMAT;
        const ushort_t* ef_h = Whi + (size_t)(l * 4 + 2) * WTMAT;
        const ushort_t* ef_l = Wlo + (size_t)(l * 4 + 2) * WTMAT;
        const ushort_t* ec_h = Whi + (size_t)(l * 4 + 3) * WTMAT;
        const ushort_t* ec_l = Wlo + (size_t)(l * 4 + 3) * WTMAT;

        // node stage
        k_proj<<<NA / 16, 512, 0, stream>>>(hc, nf_h, nf_l, nc_h, nc_l,
                                            bnf + l * FN, bnc + l * FN,
                                            Pfi, Pfj, Pci, Pcj);
        if (l == 0)
            k_pass<1, 1, 0><<<NA / 2, 512, 0, stream>>>(
                e, e, dist, nbr, Pfi, Pfj, Pci, Pcj,
                nf_h + EPART, nf_l + EPART, nc_h + EPART, nc_l + EPART,
                hc, hn, nullptr, nullptr, nullptr, nullptr, nullptr, nullptr, nullptr);
        else
            k_pass<1, 0, 0><<<NA / 2, 512, 0, stream>>>(
                e, e, dist, nbr, Pfi, Pfj, Pci, Pcj,
                nf_h + EPART, nf_l + EPART, nc_h + EPART, nc_l + EPART,
                hc, hn, nullptr, nullptr, nullptr, nullptr, nullptr, nullptr, nullptr);

        // edge stage
        k_proj<<<NA / 16, 512, 0, stream>>>(hn, ef_h, ef_l, ec_h, ec_l,
                                            bef + l * FN, bec + l * FN,
                                            Pfi, Pfj, Pci, Pcj);
        if (l < 2)
            k_pass<0, 0, 0><<<NA / 2, 512, 0, stream>>>(
                e, e, dist, nbr, Pfi, Pfj, Pci, Pcj,
                ef_h + EPART, ef_l + EPART, ec_h + EPART, ec_l + EPART,
                nullptr, nullptr, nullptr, nullptr, nullptr, nullptr, nullptr, nullptr, nullptr);
        else
            k_pass<0, 0, 1><<<NA / 2, 512, 0, stream>>>(
                e, e, dist, nbr, Pfi, Pfj, Pci, Pcj,
                ef_h + EPART, ef_l + EPART, ec_h + EPART, ec_l + EPART,
                nullptr, nullptr, Wo1h, Wo1l, bo1, Wo2, bo2, unit, out);

        float* t = hc; hc = hn; hn = t;
    }
}

// Round 6
// 672.314 us; speedup vs baseline: 4.6151x; 1.0086x over previous
//
#include <hip/hip_runtime.h>
#include <math.h>

#define AT 1024
#define NBR 32
#define FN 128
#define FE 128
#define ZIN 384
#define NA 4096              // B*At
#define NEDGE (NA * NBR)     // 131072
#define WSTRIDE (ZIN * FN)   // 49152 floats per layer
#define G_ENDF 5.5f
#define WTMAT (384 * 128)    // converted matrix elements (transposed [n][k])
#define EPART (256 * 128)    // offset of e-part rows within converted matrix

typedef unsigned short ushort_t;
typedef __attribute__((ext_vector_type(8))) short bf16x8;
typedef __attribute__((ext_vector_type(4))) float f32x4;

#define LOG2E 1.4426950408889634f
#define LN2   0.6931471805599453f

// native-instruction transcendentals (v_exp_f32 / v_log_f32 / v_rcp_f32, ~1 ulp)
__device__ __forceinline__ float fexp(float x) {
    return __builtin_amdgcn_exp2f(x * LOG2E);
}
__device__ __forceinline__ float sigmoid_f(float x) {
    return __builtin_amdgcn_rcpf(1.0f + __builtin_amdgcn_exp2f(-x * LOG2E));
}
__device__ __forceinline__ float softplus_f(float x) {
    float t = __builtin_amdgcn_exp2f(-fabsf(x) * LOG2E);
    return fmaxf(x, 0.0f) + LN2 * __builtin_amdgcn_logf(1.0f + t);
}

__device__ __forceinline__ ushort_t f2bf(float f) {
    unsigned int u = __float_as_uint(f);
    u = (u + 0x7FFFu + ((u >> 16) & 1u)) >> 16;   // RTNE
    return (ushort_t)u;
}
__device__ __forceinline__ float bf2f(ushort_t h) {
    return __uint_as_float(((unsigned int)h) << 16);
}
// packed 2xfloat -> 2xbf16 in one instruction (RTNE)
__device__ __forceinline__ unsigned int cvt_pk_bf16(float a, float b) {
    unsigned int r;
    asm("v_cvt_pk_bf16_f32 %0, %1, %2" : "=v"(r) : "v"(a), "v"(b));
    return r;
}
// split-bf16 of a float pair: hi word-pair + lo word-pair
__device__ __forceinline__ void split2(float a, float b,
                                       unsigned int& hi, unsigned int& lo) {
    hi = cvt_pk_bf16(a, b);
    float ha = __uint_as_float(hi << 16);
    float hb = __uint_as_float(hi & 0xffff0000u);
    lo = cvt_pk_bf16(a - ha, b - hb);
}

// -------- h0[atom][f] = emb[Z[atom]][f] --------
__global__ __launch_bounds__(256) void k_init_h(const int* __restrict__ Z,
                                                const float* __restrict__ emb,
                                                float* __restrict__ h) {
    int idx = blockIdx.x * 256 + threadIdx.x;
    int atom = idx >> 7, f = idx & 127;
    h[idx] = emb[Z[atom] * FN + f];
}

// -------- convert all 12 weight matrices to split-bf16, transposed [n][k] --------
__global__ __launch_bounds__(256) void k_conv_w(const float* __restrict__ Wnf,
                                                const float* __restrict__ Wnc,
                                                const float* __restrict__ Wef,
                                                const float* __restrict__ Wec,
                                                ushort_t* __restrict__ Whi,
                                                ushort_t* __restrict__ Wlo) {
    const int blk = blockIdx.x;         // 0..35
    const int w = blk / 3, p = blk % 3;
    const int l = w >> 2, t = w & 3;
    const float* src = (t == 0 ? Wnf : t == 1 ? Wnc : t == 2 ? Wef : Wec)
                       + (size_t)l * WSTRIDE + (size_t)p * 128 * 128;
    __shared__ float tile[128][129];
    const int tid = threadIdx.x;
    {
        int k = tid >> 1, h = (tid & 1) * 64;
#pragma unroll
        for (int i = 0; i < 16; ++i) {
            float4 v = *(const float4*)&src[k * 128 + h + i * 4];
            tile[k][h + i * 4 + 0] = v.x; tile[k][h + i * 4 + 1] = v.y;
            tile[k][h + i * 4 + 2] = v.z; tile[k][h + i * 4 + 3] = v.w;
        }
    }
    __syncthreads();
    {
        int f = tid >> 1, kh = (tid & 1) * 64;
        size_t orow = (size_t)(w * 384 + p * 128 + f) * 128;
#pragma unroll
        for (int i = 0; i < 64; i += 4) {
            ushort4 ph, pl;
            float x0 = tile[kh + i + 0][f]; ph.x = f2bf(x0); pl.x = f2bf(x0 - bf2f(ph.x));
            float x1 = tile[kh + i + 1][f]; ph.y = f2bf(x1); pl.y = f2bf(x1 - bf2f(ph.y));
            float x2 = tile[kh + i + 2][f]; ph.z = f2bf(x2); pl.z = f2bf(x2 - bf2f(ph.z));
            float x3 = tile[kh + i + 3][f]; ph.w = f2bf(x3); pl.w = f2bf(x3 - bf2f(ph.w));
            *(ushort4*)&Whi[orow + kh + i] = ph;
            *(ushort4*)&Wlo[orow + kh + i] = pl;
        }
    }
}

// -------- Wo1 [128][64] -> Wo1t [64 n][128 k] split bf16 --------
__global__ __launch_bounds__(256) void k_conv_wo(const float* __restrict__ Wo1,
                                                 ushort_t* __restrict__ Wh,
                                                 ushort_t* __restrict__ Wl) {
    int idx = blockIdx.x * 256 + threadIdx.x;  // over 8192
    int n = idx >> 7, k = idx & 127;
    float x = Wo1[k * 64 + n];
    ushort_t h = f2bf(x);
    Wh[idx] = h;
    Wl[idx] = f2bf(x - bf2f(h));
}

// -------- MFMA projection -> interleaved Pi/Pj: [atom][col][{f,c}] --------
// block = 16 atoms, 512 thr = 8 waves; wave w covers output cols w*64..+63 of the 512-wide C
__global__ __launch_bounds__(512, 4) void k_proj(
    const float* __restrict__ h,
    const ushort_t* __restrict__ Wah, const ushort_t* __restrict__ Wal,
    const ushort_t* __restrict__ Wbh, const ushort_t* __restrict__ Wbl,
    const float* __restrict__ ba, const float* __restrict__ bb,
    float* __restrict__ Pi, float* __restrict__ Pj) {
    const int tid = threadIdx.x;
    const int a0 = blockIdx.x * 16;
    __shared__ __align__(16) ushort_t sAh[16 * 136];
    __shared__ __align__(16) ushort_t sAl[16 * 136];
    {
        int row = tid >> 5, kq = (tid & 31) * 4;
        float4 v = *(const float4*)&h[(size_t)(a0 + row) * 128 + kq];
        unsigned int h0, l0, h1, l1;
        split2(v.x, v.y, h0, l0);
        split2(v.z, v.w, h1, l1);
        *(uint2*)&sAh[row * 136 + kq] = make_uint2(h0, h1);
        *(uint2*)&sAl[row * 136 + kq] = make_uint2(l0, l1);
    }
    __syncthreads();

    const int w = tid >> 6;
    const int lane = tid & 63;
    const int lrow = lane & 15;
    const int kgrp = (lane >> 4) * 8;

    f32x4 acc[4] = {};
#pragma unroll
    for (int kk = 0; kk < 4; ++kk) {
        const int kbase = kk * 32 + kgrp;
        bf16x8 ah = *(const bf16x8*)&sAh[lrow * 136 + kbase];
        bf16x8 al = *(const bf16x8*)&sAl[lrow * 136 + kbase];
#pragma unroll
        for (int nt = 0; nt < 4; ++nt) {
            int r512 = w * 64 + nt * 16 + lrow;
            const ushort_t* bh_p = (r512 < 256) ? (Wah + (size_t)r512 * 128)
                                                : (Wbh + (size_t)(r512 - 256) * 128);
            const ushort_t* bl_p = (r512 < 256) ? (Wal + (size_t)r512 * 128)
                                                : (Wbl + (size_t)(r512 - 256) * 128);
            bf16x8 bh = *(const bf16x8*)&bh_p[kbase];
            bf16x8 bl = *(const bf16x8*)&bl_p[kbase];
            acc[nt] = __builtin_amdgcn_mfma_f32_16x16x32_bf16(ah, bh, acc[nt], 0, 0, 0);
            acc[nt] = __builtin_amdgcn_mfma_f32_16x16x32_bf16(ah, bl, acc[nt], 0, 0, 0);
            acc[nt] = __builtin_amdgcn_mfma_f32_16x16x32_bf16(al, bh, acc[nt], 0, 0, 0);
        }
    }

    // arr: 0 = Pi slot f (+ba), 1 = Pj slot f, 2 = Pi slot c (+bb), 3 = Pj slot c
    const int arr = w >> 1;
    float* dst = (arr & 1) ? Pj : Pi;
    const int slot = arr >> 1;
    const int rb = (lane >> 4) * 4;
#pragma unroll
    for (int nt = 0; nt < 4; ++nt) {
        int f = (w & 1) * 64 + nt * 16 + lrow;
        float bs = (arr == 0) ? ba[f] : (arr == 2) ? bb[f] : 0.0f;
#pragma unroll
        for (int r = 0; r < 4; ++r) {
            int row = rb + r;
            dst[((size_t)(a0 + row) * 128 + f) * 2 + slot] = acc[nt][r] + bs;
        }
    }
}

// -------- fused split-bf16 MFMA pass --------
// block = 2 atoms = 64 edge rows, 512 thr = 8 waves (2 row-grp x 4 col-grp)
template <int NODE, int FIRST, int FUSE>
__global__ __launch_bounds__(512, 4) void k_pass(
    const float* __restrict__ e_g, float* __restrict__ e_out,
    const float* __restrict__ dist, const int* __restrict__ nbr,
    const float* __restrict__ Pi, const float* __restrict__ Pj,
    const ushort_t* __restrict__ Wfh, const ushort_t* __restrict__ Wfl,
    const ushort_t* __restrict__ Wch, const ushort_t* __restrict__ Wcl,
    const float* __restrict__ h_old, float* __restrict__ h_new,
    const ushort_t* __restrict__ Wo1h, const ushort_t* __restrict__ Wo1l,
    const float* __restrict__ bo1, const float* __restrict__ Wo2,
    const float* __restrict__ bo2, const float* __restrict__ unit,
    float* __restrict__ out) {
    const int tid = threadIdx.x;
    const int a0 = blockIdx.x * 2;
    const int base = (a0 >> 10) << 10;

    __shared__ __align__(16) ushort_t sAh[64 * 136];
    __shared__ __align__(16) ushort_t sAl[64 * 136];
    __shared__ int snbr[64];
    __shared__ float sred[4][64];

    // ---- stage e (or generate from dist) -> split bf16 LDS ----
    {
        int row = tid >> 3, kq = (tid & 7) * 16;
        size_t eoff = ((size_t)(a0 * 32 + row)) * 128 + kq;
        float v[16];
        if (FIRST) {
            const float delta = G_ENDF / 127.0f;
            const float coeff = -0.5f / (delta * delta);
            float d = dist[a0 * 32 + row];
#pragma unroll
            for (int i = 0; i < 16; ++i) {
                float x = d - (float)(kq + i) * delta;
                v[i] = fexp(coeff * x * x);
            }
#pragma unroll
            for (int i = 0; i < 4; ++i)
                *(float4*)&e_out[eoff + i * 4] =
                    make_float4(v[i * 4], v[i * 4 + 1], v[i * 4 + 2], v[i * 4 + 3]);
        } else {
#pragma unroll
            for (int i = 0; i < 4; ++i) {
                float4 t = *(const float4*)&e_g[eoff + i * 4];
                v[i * 4] = t.x; v[i * 4 + 1] = t.y; v[i * 4 + 2] = t.z; v[i * 4 + 3] = t.w;
            }
        }
#pragma unroll
        for (int i = 0; i < 4; ++i) {
            unsigned int h0, l0, h1, l1;
            split2(v[i * 4 + 0], v[i * 4 + 1], h0, l0);
            split2(v[i * 4 + 2], v[i * 4 + 3], h1, l1);
            *(uint2*)&sAh[row * 136 + kq + i * 4] = make_uint2(h0, h1);
            *(uint2*)&sAl[row * 136 + kq + i * 4] = make_uint2(l0, l1);
        }
    }
    if (tid < 64) snbr[tid] = nbr[a0 * 32 + tid];
    __syncthreads();

    const int w = tid >> 6;
    const int lane = tid & 63;
    const int wr = w >> 2;        // 0..1 : 32-row group = one atom
    const int wc = w & 3;         // 0..3 : 32-col group
    const int lrow = lane & 15;
    const int kgrp = (lane >> 4) * 8;
    const int rb = (lane >> 4) * 4;

    // ---- prefetch ALL epilogue operands into registers (issued before MFMA) ----
    float2 pi_[2];
    float2 pj_[2][8];
#pragma unroll
    for (int nt = 0; nt < 2; ++nt) {
        const int nn = wc * 32 + nt * 16 + lrow;
        pi_[nt] = *(const float2*)&Pi[((size_t)(a0 + wr) * 128 + nn) * 2];
#pragma unroll
        for (int mt = 0; mt < 2; ++mt)
#pragma unroll
            for (int r = 0; r < 4; ++r) {
                const int rl = wr * 32 + mt * 16 + rb + r;
                const int j = base + snbr[rl];
                pj_[nt][mt * 4 + r] = *(const float2*)&Pj[((size_t)j * 128 + nn) * 2];
            }
    }

    f32x4 accf[2][2] = {};
    f32x4 accc[2][2] = {};

#pragma unroll
    for (int kk = 0; kk < 4; ++kk) {
        const int kbase = kk * 32 + kgrp;
        bf16x8 ah[2], al[2];
#pragma unroll
        for (int mt = 0; mt < 2; ++mt) {
            ah[mt] = *(const bf16x8*)&sAh[(wr * 32 + mt * 16 + lrow) * 136 + kbase];
            al[mt] = *(const bf16x8*)&sAl[(wr * 32 + mt * 16 + lrow) * 136 + kbase];
        }
#pragma unroll
        for (int nt = 0; nt < 2; ++nt) {
            const int nn = wc * 32 + nt * 16 + lrow;
            bf16x8 bfh = *(const bf16x8*)&Wfh[(size_t)nn * 128 + kbase];
            bf16x8 bfl = *(const bf16x8*)&Wfl[(size_t)nn * 128 + kbase];
            bf16x8 bch = *(const bf16x8*)&Wch[(size_t)nn * 128 + kbase];
            bf16x8 bcl = *(const bf16x8*)&Wcl[(size_t)nn * 128 + kbase];
#pragma unroll
            for (int mt = 0; mt < 2; ++mt) {
                accf[mt][nt] = __builtin_amdgcn_mfma_f32_16x16x32_bf16(ah[mt], bfh, accf[mt][nt], 0, 0, 0);
                accf[mt][nt] = __builtin_amdgcn_mfma_f32_16x16x32_bf16(ah[mt], bfl, accf[mt][nt], 0, 0, 0);
                accf[mt][nt] = __builtin_amdgcn_mfma_f32_16x16x32_bf16(al[mt], bfh, accf[mt][nt], 0, 0, 0);
                accc[mt][nt] = __builtin_amdgcn_mfma_f32_16x16x32_bf16(ah[mt], bch, accc[mt][nt], 0, 0, 0);
                accc[mt][nt] = __builtin_amdgcn_mfma_f32_16x16x32_bf16(ah[mt], bcl, accc[mt][nt], 0, 0, 0);
                accc[mt][nt] = __builtin_amdgcn_mfma_f32_16x16x32_bf16(al[mt], bch, accc[mt][nt], 0, 0, 0);
            }
        }
    }

    if (FUSE) __syncthreads();   // all waves done reading A before we overwrite it

    // ---- epilogue (e reconstructed from LDS split pair: err ~2^-17 rel) ----
    float hsum[2] = {0.0f, 0.0f};
#pragma unroll
    for (int nt = 0; nt < 2; ++nt) {
        const int nn = wc * 32 + nt * 16 + lrow;
#pragma unroll
        for (int mt = 0; mt < 2; ++mt) {
#pragma unroll
            for (int r = 0; r < 4; ++r) {
                const int rl = wr * 32 + mt * 16 + rb + r;
                const int idx = mt * 4 + r;
                float cf = accf[mt][nt][r] + pi_[nt].x + pj_[nt][idx].x;
                float cc = accc[mt][nt][r] + pi_[nt].y + pj_[nt][idx].y;
                float msg = sigmoid_f(cf) * softplus_f(cc);
                if (NODE) {
                    hsum[nt] += msg;
                } else {
                    const int lidx = rl * 136 + nn;
                    float eold = bf2f(sAh[lidx]) + bf2f(sAl[lidx]);
                    float enew = eold + msg;
                    if (FUSE) {
                        ushort_t hh = f2bf(enew);
                        sAh[lidx] = hh;
                        sAl[lidx] = f2bf(enew - bf2f(hh));
                    } else {
                        e_out[((size_t)(a0 * 32 + rl)) * 128 + nn] = enew;
                    }
                }
            }
        }
    }

    if (NODE) {
#pragma unroll
        for (int nt = 0; nt < 2; ++nt) {
            float v = hsum[nt];
            v += __shfl_xor(v, 16, 64);
            v += __shfl_xor(v, 32, 64);
            if (lane < 16) {
                int col = wc * 32 + nt * 16 + lane;
                h_new[(size_t)(a0 + wr) * 128 + col] =
                    h_old[(size_t)(a0 + wr) * 128 + col] + v;
            }
        }
    }

    if (FUSE) {
        __syncthreads();   // e_new fully in LDS
        f32x4 acco[2] = {};
        const int col = wc * 16 + lrow;
#pragma unroll
        for (int kk = 0; kk < 4; ++kk) {
            const int kbase = kk * 32 + kgrp;
            bf16x8 bh = *(const bf16x8*)&Wo1h[(size_t)col * 128 + kbase];
            bf16x8 bl = *(const bf16x8*)&Wo1l[(size_t)col * 128 + kbase];
#pragma unroll
            for (int mt = 0; mt < 2; ++mt) {
                bf16x8 ah = *(const bf16x8*)&sAh[(wr * 32 + mt * 16 + lrow) * 136 + kbase];
                bf16x8 al = *(const bf16x8*)&sAl[(wr * 32 + mt * 16 + lrow) * 136 + kbase];
                acco[mt] = __builtin_amdgcn_mfma_f32_16x16x32_bf16(ah, bh, acco[mt], 0, 0, 0);
                acco[mt] = __builtin_amdgcn_mfma_f32_16x16x32_bf16(ah, bl, acco[mt], 0, 0, 0);
                acco[mt] = __builtin_amdgcn_mfma_f32_16x16x32_bf16(al, bh, acco[mt], 0, 0, 0);
            }
        }
        const float b1 = bo1[col];
        const float w2 = Wo2[col];
#pragma unroll
        for (int mt = 0; mt < 2; ++mt) {
#pragma unroll
            for (int r = 0; r < 4; ++r) {
                float val = softplus_f(acco[mt][r] + b1) * w2;
                val += __shfl_xor(val, 1, 64);
                val += __shfl_xor(val, 2, 64);
                val += __shfl_xor(val, 4, 64);
                val += __shfl_xor(val, 8, 64);
                if (lrow == 0) sred[wc][wr * 32 + mt * 16 + rb + r] = val;
            }
        }
        __syncthreads();
        if (tid < 6) {
            int a = (tid < 3) ? 0 : 1;
            int c = tid - a * 3;
            float b2 = bo2[0];
            float s = 0.0f;
#pragma unroll 4
            for (int n = 0; n < 32; ++n) {
                int row = a * 32 + n;
                float fm = sred[0][row] + sred[1][row] + sred[2][row] + sred[3][row] + b2;
                s += fm * unit[((size_t)((a0 + a) * 32 + n)) * 3 + c];
            }
            out[(size_t)(a0 + a) * 3 + c] = s;
        }
    }
}

extern "C" void kernel_launch(void* const* d_in, const int* in_sizes, int n_in,
                              void* d_out, int out_size, void* d_ws, size_t ws_size,
                              hipStream_t stream) {
    const int*   Z    = (const int*)d_in[0];
    const int*   nbr  = (const int*)d_in[1];
    const float* dist = (const float*)d_in[2];
    const float* unit = (const float*)d_in[3];
    const float* emb  = (const float*)d_in[4];
    const float* Wnf  = (const float*)d_in[5];
    const float* bnf  = (const float*)d_in[6];
    const float* Wnc  = (const float*)d_in[7];
    const float* bnc  = (const float*)d_in[8];
    const float* Wef  = (const float*)d_in[9];
    const float* bef  = (const float*)d_in[10];
    const float* Wec  = (const float*)d_in[11];
    const float* bec  = (const float*)d_in[12];
    const float* Wo1  = (const float*)d_in[13];
    const float* bo1  = (const float*)d_in[14];
    const float* Wo2  = (const float*)d_in[15];
    const float* bo2  = (const float*)d_in[16];
    float* out = (float*)d_out;

    float* ws = (float*)d_ws;
    float* e   = ws;                               // NEDGE*FE (67 MB)
    float* h0  = e + (size_t)NEDGE * FE;
    float* h1  = h0 + (size_t)NA * FN;
    float* Pi  = h1 + (size_t)NA * FN;             // NA*128*2 (f,c interleaved)
    float* Pj  = Pi + (size_t)NA * FN * 2;         // NA*128*2
    ushort_t* Whi  = (ushort_t*)(Pj + (size_t)NA * FN * 2);  // 12 * 384*128
    ushort_t* Wlo  = Whi + (size_t)12 * WTMAT;
    ushort_t* Wo1h = Wlo + (size_t)12 * WTMAT;               // 64*128
    ushort_t* Wo1l = Wo1h + (size_t)64 * 128;

    k_conv_w<<<36, 256, 0, stream>>>(Wnf, Wnc, Wef, Wec, Whi, Wlo);
    k_conv_wo<<<32, 256, 0, stream>>>(Wo1, Wo1h, Wo1l);
    k_init_h<<<(NA * FN) / 256, 256, 0, stream>>>(Z, emb, h0);

    float* hc = h0;
    float* hn = h1;
    for (int l = 0; l < 3; ++l) {
        const ushort_t* nf_h = Whi + (size_t)(l * 4 + 0) * WTMAT;
        const ushort_t* nf_l = Wlo + (size_t)(l * 4 + 0) * WTMAT;
        const ushort_t* nc_h = Whi + (size_t)(l * 4 + 1) * WTMAT;
        const ushort_t* nc_l = Wlo + (size_t)(l * 4 + 1) * WTMAT;
        const ushort_t* ef_h = Whi + (size_t)(l * 4 + 2) * WTMAT;
        const ushort_t* ef_l = Wlo + (size_t)(l * 4 + 2) * WTMAT;
        const ushort_t* ec_h = Whi + (size_t)(l * 4 + 3) * WTMAT;
        const ushort_t* ec_l = Wlo + (size_t)(l * 4 + 3) * WTMAT;

        // node stage
        k_proj<<<NA / 16, 512, 0, stream>>>(hc, nf_h, nf_l, nc_h, nc_l,
                                            bnf + l * FN, bnc + l * FN, Pi, Pj);
        if (l == 0)
            k_pass<1, 1, 0><<<NA / 2, 512, 0, stream>>>(
                e, e, dist, nbr, Pi, Pj,
                nf_h + EPART, nf_l + EPART, nc_h + EPART, nc_l + EPART,
                hc, hn, nullptr, nullptr, nullptr, nullptr, nullptr, nullptr, nullptr);
        else
            k_pass<1, 0, 0><<<NA / 2, 512, 0, stream>>>(
                e, e, dist, nbr, Pi, Pj,
                nf_h + EPART, nf_l + EPART, nc_h + EPART, nc_l + EPART,
                hc, hn, nullptr, nullptr, nullptr, nullptr, nullptr, nullptr, nullptr);

        // edge stage
        k_proj<<<NA / 16, 512, 0, stream>>>(hn, ef_h, ef_l, ec_h, ec_l,
                                            bef + l * FN, bec + l * FN, Pi, Pj);
        if (l < 2)
            k_pass<0, 0, 0><<<NA / 2, 512, 0, stream>>>(
                e, e, dist, nbr, Pi, Pj,
                ef_h + EPART, ef_l + EPART, ec_h + EPART, ec_l + EPART,
                nullptr, nullptr, nullptr, nullptr, nullptr, nullptr, nullptr, nullptr, nullptr);
        else
            k_pass<0, 0, 1><<<NA / 2, 512, 0, stream>>>(
                e, e, dist, nbr, Pi, Pj,
                ef_h + EPART, ef_l + EPART, ec_h + EPART, ec_l + EPART,
                nullptr, nullptr, Wo1h, Wo1l, bo1, Wo2, bo2, unit, out);

        float* t = hc; hc = hn; hn = t;
    }
}